// Round 5
// baseline (1297.470 us; speedup 1.0000x reference)
//
#include <hip/hip_runtime.h>
#include <math.h>

#define NN 20000
#define NE 160000
#define NG 1000
#define IND 11
#define H 128
#define ED 3
#define NL 5
#define BN_EPSF 1e-5f

// ---------------- CSR build (once per call) ----------------

__global__ void deg_int_kernel(const int* __restrict__ dst, int* __restrict__ degi) {
    int e = blockIdx.x * blockDim.x + threadIdx.x;
    if (e < NE) atomicAdd(&degi[dst[e]], 1);
}

// single-block exclusive scan over degi -> row_start/cursor; also invdeg.
__global__ __launch_bounds__(256) void scan_kernel(const int* __restrict__ degi,
                                                   int* __restrict__ row_start,
                                                   int* __restrict__ cursor,
                                                   float* __restrict__ invdeg) {
    __shared__ int wsum_s[4];
    __shared__ int s_off;
    int tid = threadIdx.x;
    int lane = tid & 63, wv = tid >> 6;
    if (tid == 0) s_off = 0;
    __syncthreads();
    for (int base = 0; base < NN; base += 256) {
        int i = base + tid;
        int v = (i < NN) ? degi[i] : 0;
        int x = v;
#pragma unroll
        for (int st = 1; st < 64; st <<= 1) {
            int y = __shfl_up(x, st, 64);
            if (lane >= st) x += y;
        }
        if (lane == 63) wsum_s[wv] = x;
        __syncthreads();
        int woff = 0;
        for (int w = 0; w < wv; ++w) woff += wsum_s[w];
        int total = wsum_s[0] + wsum_s[1] + wsum_s[2] + wsum_s[3];
        int off = s_off;
        if (i < NN) {
            int excl = off + woff + x - v;
            row_start[i] = excl;
            cursor[i] = excl;
            invdeg[i] = 1.0f / (float)(v < 1 ? 1 : v);
        }
        __syncthreads();
        if (tid == 0) s_off = off + total;
        __syncthreads();
    }
    if (tid == 0) row_start[NN] = NE;
}

// packs (ea0, ea1, ea2, src) per edge into dst-sorted order
__global__ void scatter_kernel(const int* __restrict__ src, const int* __restrict__ dst,
                               const float* __restrict__ ea,
                               int* __restrict__ cursor, float4* __restrict__ csr_ea4) {
    int e = blockIdx.x * blockDim.x + threadIdx.x;
    if (e < NE) {
        int d = dst[e];
        int pos = atomicAdd(&cursor[d], 1);
        float4 r;
        r.x = ea[e * ED + 0];
        r.y = ea[e * ED + 1];
        r.z = ea[e * ED + 2];
        r.w = __int_as_float(src[e]);
        csr_ea4[pos] = r;
    }
}

// ---------------- network ----------------

__global__ __launch_bounds__(H) void hin_kernel(const float* __restrict__ x,
                                                const float* __restrict__ Win,
                                                const float* __restrict__ bin,
                                                float* __restrict__ h) {
    int n = blockIdx.x;
    int j = threadIdx.x;
    __shared__ float xr[IND];
    if (j < IND) xr[j] = x[n * IND + j];
    __syncthreads();
    float acc = bin[j];
#pragma unroll
    for (int k = 0; k < IND; ++k) acc = fmaf(xr[k], Win[k * H + j], acc);
    h[n * H + j] = acc;
}

// 16-row tile per block, 256 threads. Thread owns column pair (cp, cp+1)
// [cp = 2*(tid&63)] across all 4 tables, for 4 rows [rg = 4*(tid>>6)].
// Tables: 0=Pf (Wf[0:H]), 1=Qf (Wf[H:2H]), 2=Ps (Ws[0:H]), 3=Qs (Ws[H:2H]).
// Outputs interleaved: PD2[n][2j]=(Pf,Ps), QS2[n][2j]=(Qf,Qs).
__global__ __launch_bounds__(256, 3) void node_gemm_kernel(float* __restrict__ h,
                                                           const float* __restrict__ Wf,
                                                           const float* __restrict__ Ws,
                                                           const float* __restrict__ sum,
                                                           const float* __restrict__ sumsq,
                                                           const float* __restrict__ gamma,
                                                           const float* __restrict__ beta,
                                                           int applyBN,
                                                           float* __restrict__ PD2,
                                                           float* __restrict__ QS2) {
    __shared__ __align__(16) float za[16][H];
    int tid = threadIdx.x;
    int cp = (tid & 63) * 2;
    int rg = (tid >> 6) * 4;
    int n0 = blockIdx.x * 16;

    // stage 16 rows (optionally BN+ReLU previous layer, writing h back)
    int scol = tid & 127;
    int r0 = tid >> 7;
    if (applyBN) {
        float mu  = sum[scol] * (1.0f / NN);
        float var = sumsq[scol] * (1.0f / NN) - mu * mu;
        float sc  = gamma[scol] * rsqrtf(var + BN_EPSF);
        float sh  = beta[scol] - mu * sc;
#pragma unroll
        for (int r = r0; r < 16; r += 2) {
            size_t o = (size_t)(n0 + r) * H + scol;
            float v = fmaf(h[o], sc, sh);
            v = v > 0.0f ? v : 0.0f;
            h[o] = v;
            za[r][scol] = v;
        }
    } else {
#pragma unroll
        for (int r = r0; r < 16; r += 2) za[r][scol] = h[(size_t)(n0 + r) * H + scol];
    }
    __syncthreads();

    float acc[4][4][2];  // [row][table][col]
#pragma unroll
    for (int n = 0; n < 4; ++n)
#pragma unroll
        for (int t = 0; t < 4; ++t) { acc[n][t][0] = 0.f; acc[n][t][1] = 0.f; }

    const float* wb0 = Wf + cp;            // table 0: Wf[k][cp..cp+1]
    const float* wb1 = Wf + H * H + cp;    // table 1
    const float* wb2 = Ws + cp;            // table 2
    const float* wb3 = Ws + H * H + cp;    // table 3

    float2 cur[4][4], nxt[4][4];           // [kk][table]
#pragma unroll
    for (int kk = 0; kk < 4; ++kk) {
        cur[kk][0] = *(const float2*)&wb0[kk * H];
        cur[kk][1] = *(const float2*)&wb1[kk * H];
        cur[kk][2] = *(const float2*)&wb2[kk * H];
        cur[kk][3] = *(const float2*)&wb3[kk * H];
    }

    for (int k = 0; k < H; k += 4) {
        if (k + 4 < H) {
#pragma unroll
            for (int kk = 0; kk < 4; ++kk) {
                nxt[kk][0] = *(const float2*)&wb0[(k + 4 + kk) * H];
                nxt[kk][1] = *(const float2*)&wb1[(k + 4 + kk) * H];
                nxt[kk][2] = *(const float2*)&wb2[(k + 4 + kk) * H];
                nxt[kk][3] = *(const float2*)&wb3[(k + 4 + kk) * H];
            }
        }
#pragma unroll
        for (int n = 0; n < 4; ++n) {
            float4 z4 = *(const float4*)&za[rg + n][k];
            float zk[4] = {z4.x, z4.y, z4.z, z4.w};
#pragma unroll
            for (int kk = 0; kk < 4; ++kk)
#pragma unroll
                for (int t = 0; t < 4; ++t) {
                    acc[n][t][0] = fmaf(zk[kk], cur[kk][t].x, acc[n][t][0]);
                    acc[n][t][1] = fmaf(zk[kk], cur[kk][t].y, acc[n][t][1]);
                }
        }
#pragma unroll
        for (int kk = 0; kk < 4; ++kk)
#pragma unroll
            for (int t = 0; t < 4; ++t) cur[kk][t] = nxt[kk][t];
    }

#pragma unroll
    for (int n = 0; n < 4; ++n) {
        size_t o = (size_t)(n0 + rg + n) * (2 * H) + 2 * cp;
        float4 pd = make_float4(acc[n][0][0], acc[n][2][0], acc[n][0][1], acc[n][2][1]);
        float4 qs = make_float4(acc[n][1][0], acc[n][3][0], acc[n][1][1], acc[n][3][1]);
        *(float4*)&PD2[o] = pd;
        *(float4*)&QS2[o] = qs;
    }
}

// CSR aggregation fused with residual + BN stats. 256 threads = 2 independent
// nodes (j = tid&127, ln = tid>>7); no LDS, no barriers. Edge records are
// same-address broadcast loads; QS2 gathers are coalesced float2.
__global__ __launch_bounds__(256) void agg_fused_kernel(const int* __restrict__ row_start,
                                                        const float4* __restrict__ csr_ea4,
                                                        const float* __restrict__ Wf,
                                                        const float* __restrict__ bf,
                                                        const float* __restrict__ Ws,
                                                        const float* __restrict__ bs,
                                                        const float* __restrict__ PD2,
                                                        const float* __restrict__ QS2,
                                                        const float* __restrict__ invdeg,
                                                        float* __restrict__ h,
                                                        float* __restrict__ sum,
                                                        float* __restrict__ sumsq) {
    int j = threadIdx.x & (H - 1);
    int ln = threadIdx.x >> 7;
    float wf0 = Wf[256 * H + j], wf1 = Wf[257 * H + j], wf2 = Wf[258 * H + j];
    float ws0 = Ws[256 * H + j], ws1 = Ws[257 * H + j], ws2 = Ws[258 * H + j];
    float bfj = bf[j], bsj = bs[j];

    float ls = 0.0f, lss = 0.0f;

    for (int d = blockIdx.x * 2 + ln; d < NN; d += gridDim.x * 2) {
        int rs = row_start[d], re = row_start[d + 1];
        float2 pd = *(const float2*)&PD2[(size_t)d * (2 * H) + 2 * j];
        float fbase = pd.x + bfj;
        float sbase = pd.y + bsj;
        float acc = 0.0f;
#pragma unroll 4
        for (int t = rs; t < re; ++t) {
            float4 fe = csr_ea4[t];
            int s = __float_as_int(fe.w);
            float2 q = *(const float2*)&QS2[(size_t)s * (2 * H) + 2 * j];
            float f = fmaf(fe.x, wf0, fmaf(fe.y, wf1, fmaf(fe.z, wf2, fbase + q.x)));
            float v = fmaf(fe.x, ws0, fmaf(fe.y, ws1, fmaf(fe.z, ws2, sbase + q.y)));
            float sig = __builtin_amdgcn_rcpf(1.0f + __expf(-f));
            float sp  = fmaxf(v, 0.0f) + __logf(1.0f + __expf(-fabsf(v)));
            acc = fmaf(sig, sp, acc);
        }
        float hv = fmaf(acc, invdeg[d], h[(size_t)d * H + j]);
        h[(size_t)d * H + j] = hv;
        ls += hv;
        lss = fmaf(hv, hv, lss);
    }
    atomicAdd(&sum[j], ls);
    atomicAdd(&sumsq[j], lss);
}

// Applies last layer's BN+ReLU on the fly, pools into per-graph sums.
__global__ __launch_bounds__(H) void pool_kernel(const float* __restrict__ h,
                                                 const int* __restrict__ batch,
                                                 const float* __restrict__ sum,
                                                 const float* __restrict__ sumsq,
                                                 const float* __restrict__ gamma,
                                                 const float* __restrict__ beta,
                                                 float* __restrict__ g,
                                                 float* __restrict__ cnt) {
    int j = threadIdx.x;
    float mu  = sum[j] * (1.0f / NN);
    float var = sumsq[j] * (1.0f / NN) - mu * mu;
    float sc  = gamma[j] * rsqrtf(var + BN_EPSF);
    float sh  = beta[j] - mu * sc;
    for (int n = blockIdx.x; n < NN; n += gridDim.x) {
        int b = batch[n];
        float v = fmaf(h[(size_t)n * H + j], sc, sh);
        v = v > 0.0f ? v : 0.0f;
        atomicAdd(&g[(size_t)b * H + j], v);
        if (j == 0) atomicAdd(&cnt[b], 1.0f);
    }
}

__global__ __launch_bounds__(H) void mlp_kernel(const float* __restrict__ g,
                                                const float* __restrict__ cnt,
                                                const float* __restrict__ W1,
                                                const float* __restrict__ b1,
                                                const float* __restrict__ W2,
                                                const float* __restrict__ b2,
                                                const float* __restrict__ W3,
                                                const float* __restrict__ b3,
                                                float* __restrict__ out) {
    int gid = blockIdx.x, j = threadIdx.x;
    __shared__ float s1[H];
    __shared__ float s2[H];
    __shared__ float wsum[2];
    float c = cnt[gid];
    c = c < 1.0f ? 1.0f : c;
    s1[j] = g[gid * H + j] / c;
    __syncthreads();
    float a = b1[j];
    for (int k = 0; k < H; ++k) a = fmaf(s1[k], W1[k * H + j], a);
    a = a > 0.0f ? a : 0.0f;
    s2[j] = a;
    __syncthreads();
    float t = b2[j];
    for (int k = 0; k < H; ++k) t = fmaf(s2[k], W2[k * H + j], t);
    t = t > 0.0f ? t : 0.0f;
    float p = t * W3[j];
    for (int off = 32; off > 0; off >>= 1) p += __shfl_down(p, off, 64);
    if ((j & 63) == 0) wsum[j >> 6] = p;
    __syncthreads();
    if (j == 0) out[gid] = wsum[0] + wsum[1] + b3[0];
}

extern "C" void kernel_launch(void* const* d_in, const int* in_sizes, int n_in,
                              void* d_out, int out_size, void* d_ws, size_t ws_size,
                              hipStream_t stream) {
    const float* x     = (const float*)d_in[0];
    const int*   ei    = (const int*)d_in[1];
    const int*   srcp  = ei;        // edge_index[0] = source (x_j)
    const int*   dstp  = ei + NE;   // edge_index[1] = target (aggregation index)
    const int*   batch = (const int*)d_in[2];
    const float* ea    = (const float*)d_in[3];
    const float* Win   = (const float*)d_in[4];
    const float* bin   = (const float*)d_in[5];
    const float* Wf    = (const float*)d_in[6];
    const float* bf    = (const float*)d_in[7];
    const float* Ws    = (const float*)d_in[8];
    const float* bs    = (const float*)d_in[9];
    const float* gamma = (const float*)d_in[10];
    const float* beta  = (const float*)d_in[11];
    const float* W1    = (const float*)d_in[12];
    const float* b1    = (const float*)d_in[13];
    const float* W2    = (const float*)d_in[14];
    const float* b2    = (const float*)d_in[15];
    const float* W3    = (const float*)d_in[16];
    const float* b3    = (const float*)d_in[17];
    float* out = (float*)d_out;

    const size_t NH = (size_t)NN * H;
    float* wsp   = (float*)d_ws;
    float* h     = wsp;                 // NN*H
    float* PD2   = h + NH;              // NN*2H
    float* QS2   = PD2 + 2 * NH;        // NN*2H
    float* invdeg= QS2 + 2 * NH;        // NN
    float* sum   = invdeg + NN;         // H
    float* sumsq = sum + H;             // H
    float* g     = sumsq + H;           // NG*H
    float* cnt   = g + (size_t)NG * H;  // NG
    float4* csr_ea4 = (float4*)(cnt + NG);       // NE float4
    int* degi      = (int*)(csr_ea4 + NE);       // NN
    int* row_start = degi + NN;                  // NN+1
    int* cursor    = row_start + NN + 1;         // NN

    // ---- CSR build (topology fixed across layers) ----
    hipMemsetAsync(degi, 0, NN * sizeof(int), stream);
    deg_int_kernel<<<(NE + 255) / 256, 256, 0, stream>>>(dstp, degi);
    scan_kernel<<<1, 256, 0, stream>>>(degi, row_start, cursor, invdeg);
    scatter_kernel<<<(NE + 255) / 256, 256, 0, stream>>>(srcp, dstp, ea, cursor, csr_ea4);

    hin_kernel<<<NN, H, 0, stream>>>(x, Win, bin, h);

    const size_t ZDH = (size_t)(2 * H + ED) * H;   // per-layer weight stride
    for (int l = 0; l < NL; ++l) {
        const float* Wfl = Wf + (size_t)l * ZDH;
        const float* Wsl = Ws + (size_t)l * ZDH;
        // reads previous layer's sum/sumsq (cleared only after this launch)
        node_gemm_kernel<<<NN / 16, 256, 0, stream>>>(h, Wfl, Wsl, sum, sumsq,
                                                      gamma + (size_t)(l ? l - 1 : 0) * H,
                                                      beta  + (size_t)(l ? l - 1 : 0) * H,
                                                      l > 0, PD2, QS2);
        hipMemsetAsync(sum, 0, 2 * H * sizeof(float), stream);
        agg_fused_kernel<<<2048, 256, 0, stream>>>(row_start, csr_ea4,
                                                   Wfl, bf + (size_t)l * H,
                                                   Wsl, bs + (size_t)l * H,
                                                   PD2, QS2, invdeg, h, sum, sumsq);
    }

    hipMemsetAsync(g, 0, ((size_t)NG * H + NG) * sizeof(float), stream);
    pool_kernel<<<2048, H, 0, stream>>>(h, batch, sum, sumsq,
                                        gamma + (size_t)(NL - 1) * H,
                                        beta + (size_t)(NL - 1) * H, g, cnt);
    mlp_kernel<<<NG, H, 0, stream>>>(g, cnt, W1, b1, W2, b2, W3, b3, out);
}

// Round 6
// 826.215 us; speedup vs baseline: 1.5704x; 1.5704x over previous
//
#include <hip/hip_runtime.h>
#include <math.h>

#define NN 20000
#define NE 160000
#define NG 1000
#define IND 11
#define H 128
#define ED 3
#define NL 5
#define NGB 32         /* nodes per block in node_gemm (two 16-row halves) */
#define BN_EPSF 1e-5f

// ---------------- CSR build (once per call) ----------------

__global__ void deg_int_kernel(const int* __restrict__ dst, int* __restrict__ degi) {
    int e = blockIdx.x * blockDim.x + threadIdx.x;
    if (e < NE) atomicAdd(&degi[dst[e]], 1);
}

// Wave-local scan + one atomicAdd per wave reserves each node's CSR segment.
// Segment placement order across waves is arbitrary — row_start[n] is explicit,
// so aggregation correctness doesn't depend on it.
__global__ __launch_bounds__(256) void reserve_kernel(const int* __restrict__ degi,
                                                      int* __restrict__ row_start,
                                                      int* __restrict__ cursor,
                                                      float* __restrict__ invdeg,
                                                      int* __restrict__ counter) {
    int n = blockIdx.x * blockDim.x + threadIdx.x;
    int lane = threadIdx.x & 63;
    int v = (n < NN) ? degi[n] : 0;
    int x = v;
#pragma unroll
    for (int st = 1; st < 64; st <<= 1) {
        int y = __shfl_up(x, st, 64);
        if (lane >= st) x += y;
    }
    int total = __shfl(x, 63, 64);
    int base = 0;
    if (lane == 63) base = atomicAdd(counter, total);
    base = __shfl(base, 63, 64);
    if (n < NN) {
        int excl = base + x - v;
        row_start[n] = excl;
        cursor[n] = excl;
        invdeg[n] = 1.0f / (float)(v < 1 ? 1 : v);
    }
}

// packs (ea0, ea1, ea2, src) per edge into dst-grouped order
__global__ void scatter_kernel(const int* __restrict__ src, const int* __restrict__ dst,
                               const float* __restrict__ ea,
                               int* __restrict__ cursor, float4* __restrict__ csr_ea4) {
    int e = blockIdx.x * blockDim.x + threadIdx.x;
    if (e < NE) {
        int d = dst[e];
        int pos = atomicAdd(&cursor[d], 1);
        float4 r;
        r.x = ea[e * ED + 0];
        r.y = ea[e * ED + 1];
        r.z = ea[e * ED + 2];
        r.w = __int_as_float(src[e]);
        csr_ea4[pos] = r;
    }
}

// ---------------- network ----------------

__global__ __launch_bounds__(H) void hin_kernel(const float* __restrict__ x,
                                                const float* __restrict__ Win,
                                                const float* __restrict__ bin,
                                                float* __restrict__ h) {
    int n = blockIdx.x;
    int j = threadIdx.x;
    __shared__ float xr[IND];
    if (j < IND) xr[j] = x[n * IND + j];
    __syncthreads();
    float acc = bin[j];
#pragma unroll
    for (int k = 0; k < IND; ++k) acc = fmaf(xr[k], Win[k * H + j], acc);
    h[n * H + j] = acc;
}

// R4 node_gemm (known-good). NGB rows staged in LDS (optional BN+ReLU of the
// previous layer applied in place); computes interleaved tables:
//   PD2[n][2j]=(Pf_j,Ps_j), QS2[n][2j]=(Qf_j,Qs_j).
__global__ __launch_bounds__(256, 3) void node_gemm_kernel(float* __restrict__ h,
                                                           const float* __restrict__ Wf,
                                                           const float* __restrict__ Ws,
                                                           const float* __restrict__ sum,
                                                           const float* __restrict__ sumsq,
                                                           const float* __restrict__ gamma,
                                                           const float* __restrict__ beta,
                                                           int applyBN,
                                                           float* __restrict__ PD2,
                                                           float* __restrict__ QS2) {
    __shared__ __align__(16) float za[NGB][H];
    int j = threadIdx.x & (H - 1);
    int half = threadIdx.x >> 7;
    int r0 = half * 16;
    int n0 = blockIdx.x * NGB;

    if (applyBN) {
        float mu  = sum[j] * (1.0f / NN);
        float var = sumsq[j] * (1.0f / NN) - mu * mu;
        float sc  = gamma[j] * rsqrtf(var + BN_EPSF);
        float sh  = beta[j] - mu * sc;
#pragma unroll
        for (int n = 0; n < 16; ++n) {
            size_t o = (size_t)(n0 + r0 + n) * H + j;
            float v = fmaf(h[o], sc, sh);
            v = v > 0.0f ? v : 0.0f;
            h[o] = v;
            za[r0 + n][j] = v;
        }
    } else {
#pragma unroll
        for (int n = 0; n < 16; ++n) za[r0 + n][j] = h[(size_t)(n0 + r0 + n) * H + j];
    }
    __syncthreads();

    float aPf[16], aQf[16], aPs[16], aQs[16];
#pragma unroll
    for (int n = 0; n < 16; ++n) { aPf[n] = 0.f; aQf[n] = 0.f; aPs[n] = 0.f; aQs[n] = 0.f; }

    const float* wfP = Wf + j;
    const float* wfQ = Wf + H * H + j;
    const float* wsP = Ws + j;
    const float* wsQ = Ws + H * H + j;

    float cur[16], nxt[16];
#pragma unroll
    for (int t = 0; t < 4; ++t) {
        cur[t]      = wfP[t * H];
        cur[4 + t]  = wfQ[t * H];
        cur[8 + t]  = wsP[t * H];
        cur[12 + t] = wsQ[t * H];
    }

    for (int k = 0; k < H; k += 4) {
        if (k + 4 < H) {
#pragma unroll
            for (int t = 0; t < 4; ++t) {
                nxt[t]      = wfP[(k + 4 + t) * H];
                nxt[4 + t]  = wfQ[(k + 4 + t) * H];
                nxt[8 + t]  = wsP[(k + 4 + t) * H];
                nxt[12 + t] = wsQ[(k + 4 + t) * H];
            }
        }
#pragma unroll
        for (int n = 0; n < 16; ++n) {
            float4 z4 = *(const float4*)&za[r0 + n][k];
            aPf[n] = fmaf(z4.x, cur[0],  fmaf(z4.y, cur[1],  fmaf(z4.z, cur[2],  fmaf(z4.w, cur[3],  aPf[n]))));
            aQf[n] = fmaf(z4.x, cur[4],  fmaf(z4.y, cur[5],  fmaf(z4.z, cur[6],  fmaf(z4.w, cur[7],  aQf[n]))));
            aPs[n] = fmaf(z4.x, cur[8],  fmaf(z4.y, cur[9],  fmaf(z4.z, cur[10], fmaf(z4.w, cur[11], aPs[n]))));
            aQs[n] = fmaf(z4.x, cur[12], fmaf(z4.y, cur[13], fmaf(z4.z, cur[14], fmaf(z4.w, cur[15], aQs[n]))));
        }
#pragma unroll
        for (int t = 0; t < 16; ++t) cur[t] = nxt[t];
    }

#pragma unroll
    for (int n = 0; n < 16; ++n) {
        size_t o = (size_t)(n0 + r0 + n) * (2 * H) + 2 * j;
        *(float2*)&PD2[o] = make_float2(aPf[n], aPs[n]);
        *(float2*)&QS2[o] = make_float2(aQf[n], aQs[n]);
    }
}

// Wave-autonomous CSR aggregation fused with residual + BN stats.
// One wave per node (grid-strided); lane l owns columns (2l, 2l+1).
// Edge records: one coalesced int4 per lane per 64-edge chunk (all in flight),
// broadcast via v_readlane; QS2 gather: one float4 per lane per edge.
// No barriers in the node loop; BN partials reduced via LDS atomics at exit.
__global__ __launch_bounds__(256) void agg_fused_kernel(const int* __restrict__ row_start,
                                                        const int* __restrict__ degi,
                                                        const int4* __restrict__ csr_fe,
                                                        const float* __restrict__ Wf,
                                                        const float* __restrict__ bf,
                                                        const float* __restrict__ Ws,
                                                        const float* __restrict__ bs,
                                                        const float4* __restrict__ PD2_4,
                                                        const float4* __restrict__ QS2_4,
                                                        const float* __restrict__ invdeg,
                                                        float* __restrict__ h,
                                                        float* __restrict__ sum,
                                                        float* __restrict__ sumsq) {
    __shared__ float redS[H];
    __shared__ float redQ[H];
    int tid = threadIdx.x;
    if (tid < H) { redS[tid] = 0.0f; redQ[tid] = 0.0f; }
    __syncthreads();

    int lane = tid & 63;
    int wv = tid >> 6;
    int c0 = 2 * lane;

    float2 wf0 = *(const float2*)&Wf[256 * H + c0];
    float2 wf1 = *(const float2*)&Wf[257 * H + c0];
    float2 wf2 = *(const float2*)&Wf[258 * H + c0];
    float2 ws0 = *(const float2*)&Ws[256 * H + c0];
    float2 ws1 = *(const float2*)&Ws[257 * H + c0];
    float2 ws2 = *(const float2*)&Ws[258 * H + c0];
    float2 bf2 = *(const float2*)&bf[c0];
    float2 bs2 = *(const float2*)&bs[c0];

    float ls0 = 0.f, ls1 = 0.f, lss0 = 0.f, lss1 = 0.f;

    for (int d = blockIdx.x * 4 + wv; d < NN; d += gridDim.x * 4) {
        int rs = row_start[d];
        int deg = degi[d];
        float4 pd = PD2_4[(size_t)d * 64 + lane];
        float fb0 = pd.x + bf2.x, sb0 = pd.y + bs2.x;
        float fb1 = pd.z + bf2.y, sb1 = pd.w + bs2.y;
        float acc0 = 0.0f, acc1 = 0.0f;
        for (int base = 0; base < deg; base += 64) {
            int cnt = deg - base;
            cnt = cnt < 64 ? cnt : 64;
            int idx = rs + base + (lane < cnt ? lane : 0);
            int4 fe = csr_fe[idx];
            for (int t = 0; t < cnt; ++t) {
                float ex = __int_as_float(__builtin_amdgcn_readlane(fe.x, t));
                float ey = __int_as_float(__builtin_amdgcn_readlane(fe.y, t));
                float ez = __int_as_float(__builtin_amdgcn_readlane(fe.z, t));
                int s = __builtin_amdgcn_readlane(fe.w, t);
                float4 q = QS2_4[(size_t)s * 64 + lane];
                float f0 = fmaf(ex, wf0.x, fmaf(ey, wf1.x, fmaf(ez, wf2.x, fb0 + q.x)));
                float v0 = fmaf(ex, ws0.x, fmaf(ey, ws1.x, fmaf(ez, ws2.x, sb0 + q.y)));
                float f1 = fmaf(ex, wf0.y, fmaf(ey, wf1.y, fmaf(ez, wf2.y, fb1 + q.z)));
                float v1 = fmaf(ex, ws0.y, fmaf(ey, ws1.y, fmaf(ez, ws2.y, sb1 + q.w)));
                float sig0 = __builtin_amdgcn_rcpf(1.0f + __expf(-f0));
                float sp0  = fmaxf(v0, 0.0f) + __logf(1.0f + __expf(-fabsf(v0)));
                float sig1 = __builtin_amdgcn_rcpf(1.0f + __expf(-f1));
                float sp1  = fmaxf(v1, 0.0f) + __logf(1.0f + __expf(-fabsf(v1)));
                acc0 = fmaf(sig0, sp0, acc0);
                acc1 = fmaf(sig1, sp1, acc1);
            }
        }
        float invd = invdeg[d];
        float2 hv = *(float2*)&h[(size_t)d * H + c0];
        float h0 = fmaf(acc0, invd, hv.x);
        float h1 = fmaf(acc1, invd, hv.y);
        *(float2*)&h[(size_t)d * H + c0] = make_float2(h0, h1);
        ls0 += h0; lss0 = fmaf(h0, h0, lss0);
        ls1 += h1; lss1 = fmaf(h1, h1, lss1);
    }

    atomicAdd(&redS[c0], ls0);
    atomicAdd(&redS[c0 + 1], ls1);
    atomicAdd(&redQ[c0], lss0);
    atomicAdd(&redQ[c0 + 1], lss1);
    __syncthreads();
    if (tid < H) {
        atomicAdd(&sum[tid], redS[tid]);
        atomicAdd(&sumsq[tid], redQ[tid]);
    }
}

// Applies last layer's BN+ReLU on the fly, pools into per-graph sums.
__global__ __launch_bounds__(H) void pool_kernel(const float* __restrict__ h,
                                                 const int* __restrict__ batch,
                                                 const float* __restrict__ sum,
                                                 const float* __restrict__ sumsq,
                                                 const float* __restrict__ gamma,
                                                 const float* __restrict__ beta,
                                                 float* __restrict__ g,
                                                 float* __restrict__ cnt) {
    int j = threadIdx.x;
    float mu  = sum[j] * (1.0f / NN);
    float var = sumsq[j] * (1.0f / NN) - mu * mu;
    float sc  = gamma[j] * rsqrtf(var + BN_EPSF);
    float sh  = beta[j] - mu * sc;
    for (int n = blockIdx.x; n < NN; n += gridDim.x) {
        int b = batch[n];
        float v = fmaf(h[(size_t)n * H + j], sc, sh);
        v = v > 0.0f ? v : 0.0f;
        atomicAdd(&g[(size_t)b * H + j], v);
        if (j == 0) atomicAdd(&cnt[b], 1.0f);
    }
}

__global__ __launch_bounds__(H) void mlp_kernel(const float* __restrict__ g,
                                                const float* __restrict__ cnt,
                                                const float* __restrict__ W1,
                                                const float* __restrict__ b1,
                                                const float* __restrict__ W2,
                                                const float* __restrict__ b2,
                                                const float* __restrict__ W3,
                                                const float* __restrict__ b3,
                                                float* __restrict__ out) {
    int gid = blockIdx.x, j = threadIdx.x;
    __shared__ float s1[H];
    __shared__ float s2[H];
    __shared__ float wsum[2];
    float c = cnt[gid];
    c = c < 1.0f ? 1.0f : c;
    s1[j] = g[gid * H + j] / c;
    __syncthreads();
    float a = b1[j];
    for (int k = 0; k < H; ++k) a = fmaf(s1[k], W1[k * H + j], a);
    a = a > 0.0f ? a : 0.0f;
    s2[j] = a;
    __syncthreads();
    float t = b2[j];
    for (int k = 0; k < H; ++k) t = fmaf(s2[k], W2[k * H + j], t);
    t = t > 0.0f ? t : 0.0f;
    float p = t * W3[j];
    for (int off = 32; off > 0; off >>= 1) p += __shfl_down(p, off, 64);
    if ((j & 63) == 0) wsum[j >> 6] = p;
    __syncthreads();
    if (j == 0) out[gid] = wsum[0] + wsum[1] + b3[0];
}

extern "C" void kernel_launch(void* const* d_in, const int* in_sizes, int n_in,
                              void* d_out, int out_size, void* d_ws, size_t ws_size,
                              hipStream_t stream) {
    const float* x     = (const float*)d_in[0];
    const int*   ei    = (const int*)d_in[1];
    const int*   srcp  = ei;        // edge_index[0] = source (x_j)
    const int*   dstp  = ei + NE;   // edge_index[1] = target (aggregation index)
    const int*   batch = (const int*)d_in[2];
    const float* ea    = (const float*)d_in[3];
    const float* Win   = (const float*)d_in[4];
    const float* bin   = (const float*)d_in[5];
    const float* Wf    = (const float*)d_in[6];
    const float* bf    = (const float*)d_in[7];
    const float* Ws    = (const float*)d_in[8];
    const float* bs    = (const float*)d_in[9];
    const float* gamma = (const float*)d_in[10];
    const float* beta  = (const float*)d_in[11];
    const float* W1    = (const float*)d_in[12];
    const float* b1    = (const float*)d_in[13];
    const float* W2    = (const float*)d_in[14];
    const float* b2    = (const float*)d_in[15];
    const float* W3    = (const float*)d_in[16];
    const float* b3    = (const float*)d_in[17];
    float* out = (float*)d_out;

    const size_t NH = (size_t)NN * H;
    float* wsp   = (float*)d_ws;
    float* h     = wsp;                 // NN*H
    float* PD2   = h + NH;              // NN*2H
    float* QS2   = PD2 + 2 * NH;        // NN*2H
    float* invdeg= QS2 + 2 * NH;        // NN
    float* sum   = invdeg + NN;         // H
    float* sumsq = sum + H;             // H
    float* g     = sumsq + H;           // NG*H
    float* cnt   = g + (size_t)NG * H;  // NG
    float4* csr_ea4 = (float4*)(cnt + NG);       // NE float4
    int* degi      = (int*)(csr_ea4 + NE);       // NN
    int* counter   = degi + NN;                  // 1
    int* row_start = counter + 1;                // NN
    int* cursor    = row_start + NN;             // NN

    // ---- CSR build (topology fixed across layers) ----
    hipMemsetAsync(degi, 0, (NN + 1) * sizeof(int), stream);  // degi + counter
    deg_int_kernel<<<(NE + 255) / 256, 256, 0, stream>>>(dstp, degi);
    reserve_kernel<<<(NN + 255) / 256, 256, 0, stream>>>(degi, row_start, cursor, invdeg, counter);
    scatter_kernel<<<(NE + 255) / 256, 256, 0, stream>>>(srcp, dstp, ea, cursor, csr_ea4);

    hin_kernel<<<NN, H, 0, stream>>>(x, Win, bin, h);

    const size_t ZDH = (size_t)(2 * H + ED) * H;   // per-layer weight stride
    for (int l = 0; l < NL; ++l) {
        const float* Wfl = Wf + (size_t)l * ZDH;
        const float* Wsl = Ws + (size_t)l * ZDH;
        // reads previous layer's sum/sumsq (cleared only after this launch)
        node_gemm_kernel<<<NN / NGB, 256, 0, stream>>>(h, Wfl, Wsl, sum, sumsq,
                                                       gamma + (size_t)(l ? l - 1 : 0) * H,
                                                       beta  + (size_t)(l ? l - 1 : 0) * H,
                                                       l > 0, PD2, QS2);
        hipMemsetAsync(sum, 0, 2 * H * sizeof(float), stream);
        agg_fused_kernel<<<2500, 256, 0, stream>>>(row_start, degi, (const int4*)csr_ea4,
                                                   Wfl, bf + (size_t)l * H,
                                                   Wsl, bs + (size_t)l * H,
                                                   (const float4*)PD2, (const float4*)QS2,
                                                   invdeg, h, sum, sumsq);
    }

    hipMemsetAsync(g, 0, ((size_t)NG * H + NG) * sizeof(float), stream);
    pool_kernel<<<2048, H, 0, stream>>>(h, batch, sum, sumsq,
                                        gamma + (size_t)(NL - 1) * H,
                                        beta + (size_t)(NL - 1) * H, g, cnt);
    mlp_kernel<<<NG, H, 0, stream>>>(g, cnt, W1, b1, W2, b2, W3, b3, out);
}

// Round 7
// 824.335 us; speedup vs baseline: 1.5740x; 1.0023x over previous
//
#include <hip/hip_runtime.h>
#include <math.h>

#define NN 20000
#define NE 160000
#define NG 1000
#define IND 11
#define H 128
#define ED 3
#define NL 5
#define ZDH (259*128)
#define BN_EPSF 1e-5f

typedef unsigned short ushort_t;
typedef __attribute__((ext_vector_type(8))) short bf8_t;
typedef __attribute__((ext_vector_type(4))) float f4_t;

__device__ inline ushort_t f2bf(float x) {
    unsigned int u = __float_as_uint(x);
    unsigned int r = (u + 0x7fffu + ((u >> 16) & 1u)) >> 16;
    return (ushort_t)r;
}
__device__ inline float bf2f(ushort_t b) {
    return __uint_as_float(((unsigned int)b) << 16);
}

// ---------------- CSR build (once per call) ----------------

__global__ void deg_int_kernel(const int* __restrict__ dst, int* __restrict__ degi) {
    int e = blockIdx.x * blockDim.x + threadIdx.x;
    if (e < NE) atomicAdd(&degi[dst[e]], 1);
}

__global__ __launch_bounds__(256) void reserve_kernel(const int* __restrict__ degi,
                                                      int* __restrict__ row_start,
                                                      int* __restrict__ cursor,
                                                      float* __restrict__ invdeg,
                                                      int* __restrict__ counter) {
    int n = blockIdx.x * blockDim.x + threadIdx.x;
    int lane = threadIdx.x & 63;
    int v = (n < NN) ? degi[n] : 0;
    int x = v;
#pragma unroll
    for (int st = 1; st < 64; st <<= 1) {
        int y = __shfl_up(x, st, 64);
        if (lane >= st) x += y;
    }
    int total = __shfl(x, 63, 64);
    int base = 0;
    if (lane == 63) base = atomicAdd(counter, total);
    base = __shfl(base, 63, 64);
    if (n < NN) {
        int excl = base + x - v;
        row_start[n] = excl;
        cursor[n] = excl;
        invdeg[n] = 1.0f / (float)(v < 1 ? 1 : v);
    }
}

__global__ void scatter_kernel(const int* __restrict__ src, const int* __restrict__ dst,
                               const float* __restrict__ ea,
                               int* __restrict__ cursor, float4* __restrict__ csr_ea4) {
    int e = blockIdx.x * blockDim.x + threadIdx.x;
    if (e < NE) {
        int d = dst[e];
        int pos = atomicAdd(&cursor[d], 1);
        float4 r;
        r.x = ea[e * ED + 0];
        r.y = ea[e * ED + 1];
        r.z = ea[e * ED + 2];
        r.w = __int_as_float(src[e]);
        csr_ea4[pos] = r;
    }
}

// ---------------- weight prep: transpose to [n][k] bf16 hi/lo ----------------
// n-table order per layer: [0:Pf(Wf k<128)][1:Ps(Ws k<128)][2:Qf(Wf k>=128)][3:Qs(Ws k>=128)]
__global__ void wprep_kernel(const float* __restrict__ Wf, const float* __restrict__ Ws,
                             ushort_t* __restrict__ Wt_hi, ushort_t* __restrict__ Wt_lo) {
    int idx = blockIdx.x * 256 + threadIdx.x;   // l*65536 + n*128 + k
    if (idx >= NL * 512 * H) return;
    int k = idx & 127;
    int n = (idx >> 7) & 511;
    int l = idx >> 16;
    int t = n >> 7, j = n & 127;
    const float* W = (t == 0 || t == 2) ? Wf : Ws;
    int krow = (t < 2) ? k : (H + k);
    float v = W[(size_t)l * ZDH + krow * H + j];
    ushort_t hi = f2bf(v);
    Wt_hi[idx] = hi;
    Wt_lo[idx] = f2bf(v - bf2f(hi));
}

// ---------------- network ----------------

__global__ __launch_bounds__(H) void hin_kernel(const float* __restrict__ x,
                                                const float* __restrict__ Win,
                                                const float* __restrict__ bin,
                                                float* __restrict__ h,
                                                ushort_t* __restrict__ h_hi,
                                                ushort_t* __restrict__ h_lo) {
    int n = blockIdx.x;
    int j = threadIdx.x;
    __shared__ float xr[IND];
    if (j < IND) xr[j] = x[n * IND + j];
    __syncthreads();
    float acc = bin[j];
#pragma unroll
    for (int k = 0; k < IND; ++k) acc = fmaf(xr[k], Win[k * H + j], acc);
    size_t o = (size_t)n * H + j;
    h[o] = acc;
    ushort_t hi = f2bf(acc);
    h_hi[o] = hi;
    h_lo[o] = f2bf(acc - bf2f(hi));
}

// MFMA node GEMM, bf16x3 split: D = Ahi*Bhi + Alo*Bhi + Ahi*Blo (fp32 acc).
// Block 256 thr = 4 waves; M-tile 32 rows; wave w owns table w (128 cols).
// A[m=lane&15][k=quad*8+j] from h_hi/h_lo [NN][128]; B[n=lane&15][k] from
// Wt [n][k]. C/D: col=lane&15, row=quad*4+reg.
__global__ __launch_bounds__(256) void node_gemm_mfma(const ushort_t* __restrict__ h_hi,
                                                      const ushort_t* __restrict__ h_lo,
                                                      const ushort_t* __restrict__ Wt_hi,
                                                      const ushort_t* __restrict__ Wt_lo,
                                                      float* __restrict__ PD2,
                                                      float* __restrict__ QS2) {
    int wave = threadIdx.x >> 6;
    int lane = threadIdx.x & 63;
    int sub = lane & 15;
    int quad = lane >> 4;
    int m0 = blockIdx.x * 32;

    f4_t acc[2][8];
#pragma unroll
    for (int a = 0; a < 2; ++a)
#pragma unroll
        for (int b = 0; b < 8; ++b) acc[a][b] = (f4_t){0.f, 0.f, 0.f, 0.f};

    const ushort_t* wh = Wt_hi + (size_t)wave * 128 * H;
    const ushort_t* wl = Wt_lo + (size_t)wave * 128 * H;

    for (int ks = 0; ks < 4; ++ks) {
        int kb = ks * 32 + quad * 8;
        bf8_t aHi[2], aLo[2];
#pragma unroll
        for (int mt = 0; mt < 2; ++mt) {
            size_t ao = (size_t)(m0 + mt * 16 + sub) * H + kb;
            aHi[mt] = *(const bf8_t*)(h_hi + ao);
            aLo[mt] = *(const bf8_t*)(h_lo + ao);
        }
#pragma unroll
        for (int nt = 0; nt < 8; ++nt) {
            size_t bo = (size_t)(nt * 16 + sub) * H + kb;
            bf8_t bHi = *(const bf8_t*)(wh + bo);
            bf8_t bLo = *(const bf8_t*)(wl + bo);
#pragma unroll
            for (int mt = 0; mt < 2; ++mt) {
                acc[mt][nt] = __builtin_amdgcn_mfma_f32_16x16x32_bf16(aHi[mt], bHi, acc[mt][nt], 0, 0, 0);
                acc[mt][nt] = __builtin_amdgcn_mfma_f32_16x16x32_bf16(aLo[mt], bHi, acc[mt][nt], 0, 0, 0);
                acc[mt][nt] = __builtin_amdgcn_mfma_f32_16x16x32_bf16(aHi[mt], bLo, acc[mt][nt], 0, 0, 0);
            }
        }
    }

    float* outp = (wave < 2) ? PD2 : QS2;
    int par = wave & 1;
#pragma unroll
    for (int mt = 0; mt < 2; ++mt)
#pragma unroll
        for (int nt = 0; nt < 8; ++nt) {
            int col2 = 2 * (nt * 16 + sub) + par;
#pragma unroll
            for (int r = 0; r < 4; ++r) {
                int row = m0 + mt * 16 + quad * 4 + r;
                outp[(size_t)row * 256 + col2] = acc[mt][nt][r];
            }
        }
}

// Wave-per-node CSR aggregation, residual + BN stats. Lane l owns cols (2l,2l+1).
// Up to 16 q-rows prefetched per chunk before compute (breaks the per-edge
// serial load chain); edge records broadcast via readlane.
__global__ __launch_bounds__(256) void agg_fused_kernel(const int* __restrict__ row_start,
                                                        const int* __restrict__ degi,
                                                        const int4* __restrict__ csr_fe,
                                                        const float* __restrict__ Wf,
                                                        const float* __restrict__ bf,
                                                        const float* __restrict__ Ws,
                                                        const float* __restrict__ bs,
                                                        const float4* __restrict__ PD2_4,
                                                        const float4* __restrict__ QS2_4,
                                                        const float* __restrict__ invdeg,
                                                        float* __restrict__ h,
                                                        float* __restrict__ sum,
                                                        float* __restrict__ sumsq) {
    __shared__ float redS[H];
    __shared__ float redQ[H];
    int tid = threadIdx.x;
    if (tid < H) { redS[tid] = 0.0f; redQ[tid] = 0.0f; }
    __syncthreads();

    int lane = tid & 63;
    int wv = tid >> 6;
    int c0 = 2 * lane;

    float2 wf0 = *(const float2*)&Wf[256 * H + c0];
    float2 wf1 = *(const float2*)&Wf[257 * H + c0];
    float2 wf2 = *(const float2*)&Wf[258 * H + c0];
    float2 ws0 = *(const float2*)&Ws[256 * H + c0];
    float2 ws1 = *(const float2*)&Ws[257 * H + c0];
    float2 ws2 = *(const float2*)&Ws[258 * H + c0];
    float2 bf2_ = *(const float2*)&bf[c0];
    float2 bs2_ = *(const float2*)&bs[c0];

    float ls0 = 0.f, ls1 = 0.f, lss0 = 0.f, lss1 = 0.f;

    for (int d = blockIdx.x * 4 + wv; d < NN; d += gridDim.x * 4) {
        int rs = row_start[d];
        int deg = degi[d];
        float4 pd = PD2_4[(size_t)d * 64 + lane];
        float fb0 = pd.x + bf2_.x, sb0 = pd.y + bs2_.x;
        float fb1 = pd.z + bf2_.y, sb1 = pd.w + bs2_.y;
        float acc0 = 0.0f, acc1 = 0.0f;
        for (int base = 0; base < deg; base += 64) {
            int cnt = deg - base;
            cnt = cnt < 64 ? cnt : 64;
            int4 fe = csr_fe[rs + base + (lane < cnt ? lane : 0)];
            float4 q[16];
#pragma unroll
            for (int i = 0; i < 16; ++i) {
                if (i < cnt) {
                    int s = __builtin_amdgcn_readlane(fe.w, i);
                    q[i] = QS2_4[(size_t)s * 64 + lane];
                }
            }
            for (int tb = 0; tb < cnt; tb += 16) {
                int m = cnt - tb;
                m = m < 16 ? m : 16;
#pragma unroll
                for (int i = 0; i < 16; ++i) {
                    if (i < m) {
                        int t = tb + i;
                        float ex = __int_as_float(__builtin_amdgcn_readlane(fe.x, t));
                        float ey = __int_as_float(__builtin_amdgcn_readlane(fe.y, t));
                        float ez = __int_as_float(__builtin_amdgcn_readlane(fe.z, t));
                        float4 qq = q[i];
                        float f0 = fmaf(ex, wf0.x, fmaf(ey, wf1.x, fmaf(ez, wf2.x, fb0 + qq.x)));
                        float v0 = fmaf(ex, ws0.x, fmaf(ey, ws1.x, fmaf(ez, ws2.x, sb0 + qq.y)));
                        float f1 = fmaf(ex, wf0.y, fmaf(ey, wf1.y, fmaf(ez, wf2.y, fb1 + qq.z)));
                        float v1 = fmaf(ex, ws0.y, fmaf(ey, ws1.y, fmaf(ez, ws2.y, sb1 + qq.w)));
                        float sig0 = __builtin_amdgcn_rcpf(1.0f + __expf(-f0));
                        float sp0  = fmaxf(v0, 0.0f) + __logf(1.0f + __expf(-fabsf(v0)));
                        float sig1 = __builtin_amdgcn_rcpf(1.0f + __expf(-f1));
                        float sp1  = fmaxf(v1, 0.0f) + __logf(1.0f + __expf(-fabsf(v1)));
                        acc0 = fmaf(sig0, sp0, acc0);
                        acc1 = fmaf(sig1, sp1, acc1);
                    }
                }
                int nb = tb + 16;
                if (nb < cnt) {
                    int mm = cnt - nb;
                    mm = mm < 16 ? mm : 16;
#pragma unroll
                    for (int i = 0; i < 16; ++i) {
                        if (i < mm) {
                            int s = __builtin_amdgcn_readlane(fe.w, nb + i);
                            q[i] = QS2_4[(size_t)s * 64 + lane];
                        }
                    }
                }
            }
        }
        float invd = invdeg[d];
        float2 hv = *(float2*)&h[(size_t)d * H + c0];
        float h0 = fmaf(acc0, invd, hv.x);
        float h1 = fmaf(acc1, invd, hv.y);
        *(float2*)&h[(size_t)d * H + c0] = make_float2(h0, h1);
        ls0 += h0; lss0 = fmaf(h0, h0, lss0);
        ls1 += h1; lss1 = fmaf(h1, h1, lss1);
    }

    atomicAdd(&redS[c0], ls0);
    atomicAdd(&redS[c0 + 1], ls1);
    atomicAdd(&redQ[c0], lss0);
    atomicAdd(&redQ[c0 + 1], lss1);
    __syncthreads();
    if (tid < H) {
        atomicAdd(&sum[tid], redS[tid]);
        atomicAdd(&sumsq[tid], redQ[tid]);
    }
}

// BN+ReLU in place on h, also emits bf16 hi/lo for the next layer's MFMA.
__global__ __launch_bounds__(256) void bnconv_kernel(float* __restrict__ h,
                                                     const float* __restrict__ sum,
                                                     const float* __restrict__ sumsq,
                                                     const float* __restrict__ gamma,
                                                     const float* __restrict__ beta,
                                                     ushort_t* __restrict__ h_hi,
                                                     ushort_t* __restrict__ h_lo) {
    int idx0 = blockIdx.x * 256 + threadIdx.x;
    int j = idx0 & 127;
    float mu  = sum[j] * (1.0f / NN);
    float var = sumsq[j] * (1.0f / NN) - mu * mu;
    float sc  = gamma[j] * rsqrtf(var + BN_EPSF);
    float sh  = beta[j] - mu * sc;
    for (int idx = idx0; idx < NN * H; idx += gridDim.x * 256) {
        float v = fmaf(h[idx], sc, sh);
        v = v > 0.0f ? v : 0.0f;
        h[idx] = v;
        ushort_t hi = f2bf(v);
        h_hi[idx] = hi;
        h_lo[idx] = f2bf(v - bf2f(hi));
    }
}

__global__ __launch_bounds__(H) void pool_kernel(const float* __restrict__ h,
                                                 const int* __restrict__ batch,
                                                 const float* __restrict__ sum,
                                                 const float* __restrict__ sumsq,
                                                 const float* __restrict__ gamma,
                                                 const float* __restrict__ beta,
                                                 float* __restrict__ g,
                                                 float* __restrict__ cnt) {
    int j = threadIdx.x;
    float mu  = sum[j] * (1.0f / NN);
    float var = sumsq[j] * (1.0f / NN) - mu * mu;
    float sc  = gamma[j] * rsqrtf(var + BN_EPSF);
    float sh  = beta[j] - mu * sc;
    for (int n = blockIdx.x; n < NN; n += gridDim.x) {
        int b = batch[n];
        float v = fmaf(h[(size_t)n * H + j], sc, sh);
        v = v > 0.0f ? v : 0.0f;
        atomicAdd(&g[(size_t)b * H + j], v);
        if (j == 0) atomicAdd(&cnt[b], 1.0f);
    }
}

__global__ __launch_bounds__(H) void mlp_kernel(const float* __restrict__ g,
                                                const float* __restrict__ cnt,
                                                const float* __restrict__ W1,
                                                const float* __restrict__ b1,
                                                const float* __restrict__ W2,
                                                const float* __restrict__ b2,
                                                const float* __restrict__ W3,
                                                const float* __restrict__ b3,
                                                float* __restrict__ out) {
    int gid = blockIdx.x, j = threadIdx.x;
    __shared__ float s1[H];
    __shared__ float s2[H];
    __shared__ float wsum[2];
    float c = cnt[gid];
    c = c < 1.0f ? 1.0f : c;
    s1[j] = g[gid * H + j] / c;
    __syncthreads();
    float a = b1[j];
    for (int k = 0; k < H; ++k) a = fmaf(s1[k], W1[k * H + j], a);
    a = a > 0.0f ? a : 0.0f;
    s2[j] = a;
    __syncthreads();
    float t = b2[j];
    for (int k = 0; k < H; ++k) t = fmaf(s2[k], W2[k * H + j], t);
    t = t > 0.0f ? t : 0.0f;
    float p = t * W3[j];
    for (int off = 32; off > 0; off >>= 1) p += __shfl_down(p, off, 64);
    if ((j & 63) == 0) wsum[j >> 6] = p;
    __syncthreads();
    if (j == 0) out[gid] = wsum[0] + wsum[1] + b3[0];
}

extern "C" void kernel_launch(void* const* d_in, const int* in_sizes, int n_in,
                              void* d_out, int out_size, void* d_ws, size_t ws_size,
                              hipStream_t stream) {
    const float* x     = (const float*)d_in[0];
    const int*   ei    = (const int*)d_in[1];
    const int*   srcp  = ei;        // edge_index[0] = source (x_j)
    const int*   dstp  = ei + NE;   // edge_index[1] = target (aggregation index)
    const int*   batch = (const int*)d_in[2];
    const float* ea    = (const float*)d_in[3];
    const float* Win   = (const float*)d_in[4];
    const float* bin   = (const float*)d_in[5];
    const float* Wf    = (const float*)d_in[6];
    const float* bf    = (const float*)d_in[7];
    const float* Ws    = (const float*)d_in[8];
    const float* bs    = (const float*)d_in[9];
    const float* gamma = (const float*)d_in[10];
    const float* beta  = (const float*)d_in[11];
    const float* W1    = (const float*)d_in[12];
    const float* b1    = (const float*)d_in[13];
    const float* W2    = (const float*)d_in[14];
    const float* b2    = (const float*)d_in[15];
    const float* W3    = (const float*)d_in[16];
    const float* b3    = (const float*)d_in[17];
    float* out = (float*)d_out;

    const size_t NH = (size_t)NN * H;
    float* wsp = (float*)d_ws;
    size_t off = 0;
    float* h      = wsp + off; off += NH;
    float* PD2    = wsp + off; off += 2 * NH;
    float* QS2    = wsp + off; off += 2 * NH;
    float* invdeg = wsp + off; off += NN;
    float* sum    = wsp + off; off += H;
    float* sumsq  = wsp + off; off += H;
    float* g      = wsp + off; off += (size_t)NG * H;
    float* cnt    = wsp + off; off += NG;
    off = (off + 3) & ~(size_t)3;
    float4* csr_ea4 = (float4*)(wsp + off); off += (size_t)NE * 4;
    int* degi      = (int*)(wsp + off); off += NN;
    int* counter   = (int*)(wsp + off); off += 1;
    int* row_start = (int*)(wsp + off); off += NN;
    int* cursor    = (int*)(wsp + off); off += NN;
    off = (off + 3) & ~(size_t)3;
    ushort_t* h_hi  = (ushort_t*)(wsp + off); off += NH / 2;
    ushort_t* h_lo  = (ushort_t*)(wsp + off); off += NH / 2;
    ushort_t* Wt_hi = (ushort_t*)(wsp + off); off += (size_t)NL * 512 * H / 2;
    ushort_t* Wt_lo = (ushort_t*)(wsp + off); off += (size_t)NL * 512 * H / 2;

    // ---- CSR + weight prep (topology/weights fixed across layers) ----
    hipMemsetAsync(degi, 0, (NN + 1) * sizeof(int), stream);  // degi + counter
    deg_int_kernel<<<(NE + 255) / 256, 256, 0, stream>>>(dstp, degi);
    reserve_kernel<<<(NN + 255) / 256, 256, 0, stream>>>(degi, row_start, cursor, invdeg, counter);
    scatter_kernel<<<(NE + 255) / 256, 256, 0, stream>>>(srcp, dstp, ea, cursor, csr_ea4);
    wprep_kernel<<<(NL * 512 * H + 255) / 256, 256, 0, stream>>>(Wf, Ws, Wt_hi, Wt_lo);

    hin_kernel<<<NN, H, 0, stream>>>(x, Win, bin, h, h_hi, h_lo);

    for (int l = 0; l < NL; ++l) {
        node_gemm_mfma<<<NN / 32, 256, 0, stream>>>(h_hi, h_lo,
                                                    Wt_hi + (size_t)l * 512 * H,
                                                    Wt_lo + (size_t)l * 512 * H,
                                                    PD2, QS2);
        hipMemsetAsync(sum, 0, 2 * H * sizeof(float), stream);
        agg_fused_kernel<<<2500, 256, 0, stream>>>(row_start, degi, (const int4*)csr_ea4,
                                                   Wf + (size_t)l * ZDH, bf + (size_t)l * H,
                                                   Ws + (size_t)l * ZDH, bs + (size_t)l * H,
                                                   (const float4*)PD2, (const float4*)QS2,
                                                   invdeg, h, sum, sumsq);
        if (l < NL - 1)
            bnconv_kernel<<<1280, 256, 0, stream>>>(h, sum, sumsq,
                                                    gamma + (size_t)l * H, beta + (size_t)l * H,
                                                    h_hi, h_lo);
    }

    hipMemsetAsync(g, 0, ((size_t)NG * H + NG) * sizeof(float), stream);
    pool_kernel<<<2048, H, 0, stream>>>(h, batch, sum, sumsq,
                                        gamma + (size_t)(NL - 1) * H,
                                        beta + (size_t)(NL - 1) * H, g, cnt);
    mlp_kernel<<<NG, H, 0, stream>>>(g, cnt, W1, b1, W2, b2, W3, b3, out);
}

// Round 8
// 676.511 us; speedup vs baseline: 1.9179x; 1.2185x over previous
//
#include <hip/hip_runtime.h>
#include <math.h>

#define NN 20000
#define NE 160000
#define NG 1000
#define IND 11
#define H 128
#define ED 3
#define NL 5
#define ZDH (259*128)
#define BN_EPSF 1e-5f

typedef unsigned short ushort_t;
typedef __attribute__((ext_vector_type(8))) short bf8_t;
typedef __attribute__((ext_vector_type(4))) float f4_t;

__device__ inline ushort_t f2bf(float x) {
    unsigned int u = __float_as_uint(x);
    unsigned int r = (u + 0x7fffu + ((u >> 16) & 1u)) >> 16;
    return (ushort_t)r;
}
__device__ inline float bf2f(ushort_t b) {
    return __uint_as_float(((unsigned int)b) << 16);
}

// ---------------- CSR build (once per call) ----------------

__global__ void deg_int_kernel(const int* __restrict__ dst, int* __restrict__ degi) {
    int e = blockIdx.x * blockDim.x + threadIdx.x;
    if (e < NE) atomicAdd(&degi[dst[e]], 1);
}

__global__ __launch_bounds__(256) void reserve_kernel(const int* __restrict__ degi,
                                                      int* __restrict__ row_start,
                                                      int* __restrict__ cursor,
                                                      float* __restrict__ invdeg,
                                                      int* __restrict__ counter) {
    int n = blockIdx.x * blockDim.x + threadIdx.x;
    int lane = threadIdx.x & 63;
    int v = (n < NN) ? degi[n] : 0;
    int x = v;
#pragma unroll
    for (int st = 1; st < 64; st <<= 1) {
        int y = __shfl_up(x, st, 64);
        if (lane >= st) x += y;
    }
    int total = __shfl(x, 63, 64);
    int base = 0;
    if (lane == 63) base = atomicAdd(counter, total);
    base = __shfl(base, 63, 64);
    if (n < NN) {
        int excl = base + x - v;
        row_start[n] = excl;
        cursor[n] = excl;
        invdeg[n] = 1.0f / (float)(v < 1 ? 1 : v);
    }
}

// packs (ea0,ea1,ea2,src) and dst per edge into dst-grouped order
__global__ void scatter_kernel(const int* __restrict__ src, const int* __restrict__ dst,
                               const float* __restrict__ ea,
                               int* __restrict__ cursor, float4* __restrict__ csr_ea4,
                               int* __restrict__ csr_dst) {
    int e = blockIdx.x * blockDim.x + threadIdx.x;
    if (e < NE) {
        int d = dst[e];
        int pos = atomicAdd(&cursor[d], 1);
        float4 r;
        r.x = ea[e * ED + 0];
        r.y = ea[e * ED + 1];
        r.z = ea[e * ED + 2];
        r.w = __int_as_float(src[e]);
        csr_ea4[pos] = r;
        csr_dst[pos] = d;
    }
}

// ---------------- weight prep: transpose to [n][k] bf16 hi/lo ----------------
__global__ void wprep_kernel(const float* __restrict__ Wf, const float* __restrict__ Ws,
                             ushort_t* __restrict__ Wt_hi, ushort_t* __restrict__ Wt_lo) {
    int idx = blockIdx.x * 256 + threadIdx.x;   // l*65536 + n*128 + k
    if (idx >= NL * 512 * H) return;
    int k = idx & 127;
    int n = (idx >> 7) & 511;
    int l = idx >> 16;
    int t = n >> 7, j = n & 127;
    const float* W = (t == 0 || t == 2) ? Wf : Ws;
    int krow = (t < 2) ? k : (H + k);
    float v = W[(size_t)l * ZDH + krow * H + j];
    ushort_t hi = f2bf(v);
    Wt_hi[idx] = hi;
    Wt_lo[idx] = f2bf(v - bf2f(hi));
}

// ---------------- network ----------------

__global__ __launch_bounds__(H) void hin_kernel(const float* __restrict__ x,
                                                const float* __restrict__ Win,
                                                const float* __restrict__ bin,
                                                float* __restrict__ h,
                                                ushort_t* __restrict__ h_hi,
                                                ushort_t* __restrict__ h_lo) {
    int n = blockIdx.x;
    int j = threadIdx.x;
    __shared__ float xr[IND];
    if (j < IND) xr[j] = x[n * IND + j];
    __syncthreads();
    float acc = bin[j];
#pragma unroll
    for (int k = 0; k < IND; ++k) acc = fmaf(xr[k], Win[k * H + j], acc);
    size_t o = (size_t)n * H + j;
    h[o] = acc;
    ushort_t hi = f2bf(acc);
    h_hi[o] = hi;
    h_lo[o] = f2bf(acc - bf2f(hi));
}

// MFMA node GEMM, bf16x3 split (unchanged from R7 — counters pending).
__global__ __launch_bounds__(256) void node_gemm_mfma(const ushort_t* __restrict__ h_hi,
                                                      const ushort_t* __restrict__ h_lo,
                                                      const ushort_t* __restrict__ Wt_hi,
                                                      const ushort_t* __restrict__ Wt_lo,
                                                      float* __restrict__ PD2,
                                                      float* __restrict__ QS2) {
    int wave = threadIdx.x >> 6;
    int lane = threadIdx.x & 63;
    int sub = lane & 15;
    int quad = lane >> 4;
    int m0 = blockIdx.x * 32;

    f4_t acc[2][8];
#pragma unroll
    for (int a = 0; a < 2; ++a)
#pragma unroll
        for (int b = 0; b < 8; ++b) acc[a][b] = (f4_t){0.f, 0.f, 0.f, 0.f};

    const ushort_t* wh = Wt_hi + (size_t)wave * 128 * H;
    const ushort_t* wl = Wt_lo + (size_t)wave * 128 * H;

    for (int ks = 0; ks < 4; ++ks) {
        int kb = ks * 32 + quad * 8;
        bf8_t aHi[2], aLo[2];
#pragma unroll
        for (int mt = 0; mt < 2; ++mt) {
            size_t ao = (size_t)(m0 + mt * 16 + sub) * H + kb;
            aHi[mt] = *(const bf8_t*)(h_hi + ao);
            aLo[mt] = *(const bf8_t*)(h_lo + ao);
        }
#pragma unroll
        for (int nt = 0; nt < 8; ++nt) {
            size_t bo = (size_t)(nt * 16 + sub) * H + kb;
            bf8_t bHi = *(const bf8_t*)(wh + bo);
            bf8_t bLo = *(const bf8_t*)(wl + bo);
#pragma unroll
            for (int mt = 0; mt < 2; ++mt) {
                acc[mt][nt] = __builtin_amdgcn_mfma_f32_16x16x32_bf16(aHi[mt], bHi, acc[mt][nt], 0, 0, 0);
                acc[mt][nt] = __builtin_amdgcn_mfma_f32_16x16x32_bf16(aLo[mt], bHi, acc[mt][nt], 0, 0, 0);
                acc[mt][nt] = __builtin_amdgcn_mfma_f32_16x16x32_bf16(aHi[mt], bLo, acc[mt][nt], 0, 0, 0);
            }
        }
    }

    float* outp = (wave < 2) ? PD2 : QS2;
    int par = wave & 1;
#pragma unroll
    for (int mt = 0; mt < 2; ++mt)
#pragma unroll
        for (int nt = 0; nt < 8; ++nt) {
            int col2 = 2 * (nt * 16 + sub) + par;
#pragma unroll
            for (int r = 0; r < 4; ++r) {
                int row = m0 + mt * 16 + quad * 4 + r;
                outp[(size_t)row * 256 + col2] = acc[mt][nt][r];
            }
        }
}

// Edge-parallel segmented CSR aggregation. Wave owns 32 consecutive CSR
// positions; lane owns cols (2l,2l+1). QS2[src] AND PD2[dst] prefetched per
// edge in an 8-deep rolling register window (pd redundancy hits L1). Segment
// boundaries are wave-uniform; flush = atomicAdd(h, acc*invdeg) off the
// critical path. Residual is folded into the atomic adds.
__global__ __launch_bounds__(256) void agg_edge_kernel(const int4* __restrict__ csr_fe,
                                                       const int* __restrict__ csr_dst,
                                                       const float* __restrict__ Wf,
                                                       const float* __restrict__ bf,
                                                       const float* __restrict__ Ws,
                                                       const float* __restrict__ bs,
                                                       const float4* __restrict__ PD2_4,
                                                       const float4* __restrict__ QS2_4,
                                                       const float* __restrict__ invdeg,
                                                       float* __restrict__ h) {
    int tid = threadIdx.x;
    int lane = tid & 63;
    int wv = tid >> 6;
    int base = (blockIdx.x * 4 + wv) * 32;
    int c0 = 2 * lane;

    float2 wf0 = *(const float2*)&Wf[256 * H + c0];
    float2 wf1 = *(const float2*)&Wf[257 * H + c0];
    float2 wf2 = *(const float2*)&Wf[258 * H + c0];
    float2 ws0 = *(const float2*)&Ws[256 * H + c0];
    float2 ws1 = *(const float2*)&Ws[257 * H + c0];
    float2 ws2 = *(const float2*)&Ws[258 * H + c0];
    float2 bf2_ = *(const float2*)&bf[c0];
    float2 bs2_ = *(const float2*)&bs[c0];

    // lanes 0..31 hold this wave's 32 edge records (readlane-broadcast below)
    int4 fe = csr_fe[base + (lane & 31)];
    int   dd = csr_dst[base + (lane & 31)];

    float4 q[8], p[8];
#pragma unroll
    for (int i = 0; i < 8; ++i) {
        int s = __builtin_amdgcn_readlane(fe.w, i);
        int d = __builtin_amdgcn_readlane(dd, i);
        q[i] = QS2_4[(size_t)s * 64 + lane];
        p[i] = PD2_4[(size_t)d * 64 + lane];
    }

    int dcur = __builtin_amdgcn_readlane(dd, 0);
    float acc0 = 0.f, acc1 = 0.f;

#pragma unroll
    for (int tb = 0; tb < 32; tb += 8) {
#pragma unroll
        for (int i = 0; i < 8; ++i) {
            int t = tb + i;
            int d = __builtin_amdgcn_readlane(dd, t);
            if (d != dcur) {   // wave-uniform branch
                float inv = invdeg[dcur];
                atomicAdd(&h[(size_t)dcur * H + c0], acc0 * inv);
                atomicAdd(&h[(size_t)dcur * H + c0 + 1], acc1 * inv);
                acc0 = 0.f; acc1 = 0.f;
                dcur = d;
            }
            float ex = __int_as_float(__builtin_amdgcn_readlane(fe.x, t));
            float ey = __int_as_float(__builtin_amdgcn_readlane(fe.y, t));
            float ez = __int_as_float(__builtin_amdgcn_readlane(fe.z, t));
            float4 qq = q[i], pp = p[i];
            if (t + 8 < 32) {   // rolling reload, 16 loads in flight
                int s2 = __builtin_amdgcn_readlane(fe.w, t + 8);
                int d2 = __builtin_amdgcn_readlane(dd, t + 8);
                q[i] = QS2_4[(size_t)s2 * 64 + lane];
                p[i] = PD2_4[(size_t)d2 * 64 + lane];
            }
            float f0 = fmaf(ex, wf0.x, fmaf(ey, wf1.x, fmaf(ez, wf2.x, pp.x + bf2_.x + qq.x)));
            float v0 = fmaf(ex, ws0.x, fmaf(ey, ws1.x, fmaf(ez, ws2.x, pp.y + bs2_.x + qq.y)));
            float f1 = fmaf(ex, wf0.y, fmaf(ey, wf1.y, fmaf(ez, wf2.y, pp.z + bf2_.y + qq.z)));
            float v1 = fmaf(ex, ws0.y, fmaf(ey, ws1.y, fmaf(ez, ws2.y, pp.w + bs2_.y + qq.w)));
            float sig0 = __builtin_amdgcn_rcpf(1.0f + __expf(-f0));
            float sp0  = fmaxf(v0, 0.0f) + __logf(1.0f + __expf(-fabsf(v0)));
            float sig1 = __builtin_amdgcn_rcpf(1.0f + __expf(-f1));
            float sp1  = fmaxf(v1, 0.0f) + __logf(1.0f + __expf(-fabsf(v1)));
            acc0 = fmaf(sig0, sp0, acc0);
            acc1 = fmaf(sig1, sp1, acc1);
        }
    }
    float inv = invdeg[dcur];
    atomicAdd(&h[(size_t)dcur * H + c0], acc0 * inv);
    atomicAdd(&h[(size_t)dcur * H + c0 + 1], acc1 * inv);
}

// per-column sum / sum-of-squares over h
__global__ __launch_bounds__(H) void stats_kernel(const float* __restrict__ h,
                                                  float* __restrict__ sum,
                                                  float* __restrict__ sumsq) {
    int j = threadIdx.x;
    float s = 0.0f, ss = 0.0f;
    for (int n = blockIdx.x; n < NN; n += gridDim.x) {
        float v = h[(size_t)n * H + j];
        s += v;
        ss = fmaf(v, v, ss);
    }
    atomicAdd(&sum[j], s);
    atomicAdd(&sumsq[j], ss);
}

// BN+ReLU in place on h, also emits bf16 hi/lo for the next layer's MFMA.
__global__ __launch_bounds__(256) void bnconv_kernel(float* __restrict__ h,
                                                     const float* __restrict__ sum,
                                                     const float* __restrict__ sumsq,
                                                     const float* __restrict__ gamma,
                                                     const float* __restrict__ beta,
                                                     ushort_t* __restrict__ h_hi,
                                                     ushort_t* __restrict__ h_lo) {
    int idx0 = blockIdx.x * 256 + threadIdx.x;
    int j = idx0 & 127;
    float mu  = sum[j] * (1.0f / NN);
    float var = sumsq[j] * (1.0f / NN) - mu * mu;
    float sc  = gamma[j] * rsqrtf(var + BN_EPSF);
    float sh  = beta[j] - mu * sc;
    for (int idx = idx0; idx < NN * H; idx += gridDim.x * 256) {
        float v = fmaf(h[idx], sc, sh);
        v = v > 0.0f ? v : 0.0f;
        h[idx] = v;
        ushort_t hi = f2bf(v);
        h_hi[idx] = hi;
        h_lo[idx] = f2bf(v - bf2f(hi));
    }
}

__global__ __launch_bounds__(H) void pool_kernel(const float* __restrict__ h,
                                                 const int* __restrict__ batch,
                                                 const float* __restrict__ sum,
                                                 const float* __restrict__ sumsq,
                                                 const float* __restrict__ gamma,
                                                 const float* __restrict__ beta,
                                                 float* __restrict__ g,
                                                 float* __restrict__ cnt) {
    int j = threadIdx.x;
    float mu  = sum[j] * (1.0f / NN);
    float var = sumsq[j] * (1.0f / NN) - mu * mu;
    float sc  = gamma[j] * rsqrtf(var + BN_EPSF);
    float sh  = beta[j] - mu * sc;
    for (int n = blockIdx.x; n < NN; n += gridDim.x) {
        int b = batch[n];
        float v = fmaf(h[(size_t)n * H + j], sc, sh);
        v = v > 0.0f ? v : 0.0f;
        atomicAdd(&g[(size_t)b * H + j], v);
        if (j == 0) atomicAdd(&cnt[b], 1.0f);
    }
}

__global__ __launch_bounds__(H) void mlp_kernel(const float* __restrict__ g,
                                                const float* __restrict__ cnt,
                                                const float* __restrict__ W1,
                                                const float* __restrict__ b1,
                                                const float* __restrict__ W2,
                                                const float* __restrict__ b2,
                                                const float* __restrict__ W3,
                                                const float* __restrict__ b3,
                                                float* __restrict__ out) {
    int gid = blockIdx.x, j = threadIdx.x;
    __shared__ float s1[H];
    __shared__ float s2[H];
    __shared__ float wsum[2];
    float c = cnt[gid];
    c = c < 1.0f ? 1.0f : c;
    s1[j] = g[gid * H + j] / c;
    __syncthreads();
    float a = b1[j];
    for (int k = 0; k < H; ++k) a = fmaf(s1[k], W1[k * H + j], a);
    a = a > 0.0f ? a : 0.0f;
    s2[j] = a;
    __syncthreads();
    float t = b2[j];
    for (int k = 0; k < H; ++k) t = fmaf(s2[k], W2[k * H + j], t);
    t = t > 0.0f ? t : 0.0f;
    float p = t * W3[j];
    for (int off = 32; off > 0; off >>= 1) p += __shfl_down(p, off, 64);
    if ((j & 63) == 0) wsum[j >> 6] = p;
    __syncthreads();
    if (j == 0) out[gid] = wsum[0] + wsum[1] + b3[0];
}

extern "C" void kernel_launch(void* const* d_in, const int* in_sizes, int n_in,
                              void* d_out, int out_size, void* d_ws, size_t ws_size,
                              hipStream_t stream) {
    const float* x     = (const float*)d_in[0];
    const int*   ei    = (const int*)d_in[1];
    const int*   srcp  = ei;        // edge_index[0] = source (x_j)
    const int*   dstp  = ei + NE;   // edge_index[1] = target (aggregation index)
    const int*   batch = (const int*)d_in[2];
    const float* ea    = (const float*)d_in[3];
    const float* Win   = (const float*)d_in[4];
    const float* bin   = (const float*)d_in[5];
    const float* Wf    = (const float*)d_in[6];
    const float* bf    = (const float*)d_in[7];
    const float* Ws    = (const float*)d_in[8];
    const float* bs    = (const float*)d_in[9];
    const float* gamma = (const float*)d_in[10];
    const float* beta  = (const float*)d_in[11];
    const float* W1    = (const float*)d_in[12];
    const float* b1    = (const float*)d_in[13];
    const float* W2    = (const float*)d_in[14];
    const float* b2    = (const float*)d_in[15];
    const float* W3    = (const float*)d_in[16];
    const float* b3    = (const float*)d_in[17];
    float* out = (float*)d_out;

    const size_t NH = (size_t)NN * H;
    float* wsp = (float*)d_ws;
    size_t off = 0;
    float* h      = wsp + off; off += NH;
    float* PD2    = wsp + off; off += 2 * NH;
    float* QS2    = wsp + off; off += 2 * NH;
    float* invdeg = wsp + off; off += NN;
    float* sum    = wsp + off; off += H;
    float* sumsq  = wsp + off; off += H;
    float* g      = wsp + off; off += (size_t)NG * H;
    float* cnt    = wsp + off; off += NG;
    off = (off + 3) & ~(size_t)3;
    float4* csr_ea4 = (float4*)(wsp + off); off += (size_t)NE * 4;
    int* degi      = (int*)(wsp + off); off += NN;
    int* counter   = (int*)(wsp + off); off += 1;
    int* row_start = (int*)(wsp + off); off += NN;
    int* cursor    = (int*)(wsp + off); off += NN;
    int* csr_dst   = (int*)(wsp + off); off += NE;
    off = (off + 3) & ~(size_t)3;
    ushort_t* h_hi  = (ushort_t*)(wsp + off); off += NH / 2;
    ushort_t* h_lo  = (ushort_t*)(wsp + off); off += NH / 2;
    ushort_t* Wt_hi = (ushort_t*)(wsp + off); off += (size_t)NL * 512 * H / 2;
    ushort_t* Wt_lo = (ushort_t*)(wsp + off); off += (size_t)NL * 512 * H / 2;

    // ---- CSR + weight prep (topology/weights fixed across layers) ----
    hipMemsetAsync(degi, 0, (NN + 1) * sizeof(int), stream);  // degi + counter
    deg_int_kernel<<<(NE + 255) / 256, 256, 0, stream>>>(dstp, degi);
    reserve_kernel<<<(NN + 255) / 256, 256, 0, stream>>>(degi, row_start, cursor, invdeg, counter);
    scatter_kernel<<<(NE + 255) / 256, 256, 0, stream>>>(srcp, dstp, ea, cursor, csr_ea4, csr_dst);
    wprep_kernel<<<(NL * 512 * H + 255) / 256, 256, 0, stream>>>(Wf, Ws, Wt_hi, Wt_lo);

    hin_kernel<<<NN, H, 0, stream>>>(x, Win, bin, h, h_hi, h_lo);

    for (int l = 0; l < NL; ++l) {
        node_gemm_mfma<<<NN / 32, 256, 0, stream>>>(h_hi, h_lo,
                                                    Wt_hi + (size_t)l * 512 * H,
                                                    Wt_lo + (size_t)l * 512 * H,
                                                    PD2, QS2);
        hipMemsetAsync(sum, 0, 2 * H * sizeof(float), stream);
        agg_edge_kernel<<<NE / 128, 256, 0, stream>>>((const int4*)csr_ea4, csr_dst,
                                                      Wf + (size_t)l * ZDH, bf + (size_t)l * H,
                                                      Ws + (size_t)l * ZDH, bs + (size_t)l * H,
                                                      (const float4*)PD2, (const float4*)QS2,
                                                      invdeg, h);
        stats_kernel<<<256, H, 0, stream>>>(h, sum, sumsq);
        if (l < NL - 1)
            bnconv_kernel<<<1280, 256, 0, stream>>>(h, sum, sumsq,
                                                    gamma + (size_t)l * H, beta + (size_t)l * H,
                                                    h_hi, h_lo);
    }

    hipMemsetAsync(g, 0, ((size_t)NG * H + NG) * sizeof(float), stream);
    pool_kernel<<<2048, H, 0, stream>>>(h, batch, sum, sumsq,
                                        gamma + (size_t)(NL - 1) * H,
                                        beta + (size_t)(NL - 1) * H, g, cnt);
    mlp_kernel<<<NG, H, 0, stream>>>(g, cnt, W1, b1, W2, b2, W3, b3, out);
}

// Round 9
// 642.429 us; speedup vs baseline: 2.0196x; 1.0531x over previous
//
#include <hip/hip_runtime.h>
#include <math.h>

#define NN 20000
#define NE 160000
#define NG 1000
#define IND 11
#define H 128
#define ED 3
#define NL 5
#define ZDH (259*128)
#define BN_EPSF 1e-5f

typedef unsigned short ushort_t;
typedef __attribute__((ext_vector_type(8))) short bf8_t;
typedef __attribute__((ext_vector_type(4))) float f4_t;

__device__ inline ushort_t f2bf(float x) {
    unsigned int u = __float_as_uint(x);
    unsigned int r = (u + 0x7fffu + ((u >> 16) & 1u)) >> 16;
    return (ushort_t)r;
}
__device__ inline float bf2f(ushort_t b) {
    return __uint_as_float(((unsigned int)b) << 16);
}

// ---------------- CSR build (once per call) ----------------

__global__ void deg_int_kernel(const int* __restrict__ dst, int* __restrict__ degi) {
    int e = blockIdx.x * blockDim.x + threadIdx.x;
    if (e < NE) atomicAdd(&degi[dst[e]], 1);
}

__global__ __launch_bounds__(256) void reserve_kernel(const int* __restrict__ degi,
                                                      int* __restrict__ row_start,
                                                      int* __restrict__ cursor,
                                                      float* __restrict__ invdeg,
                                                      int* __restrict__ counter) {
    int n = blockIdx.x * blockDim.x + threadIdx.x;
    int lane = threadIdx.x & 63;
    int v = (n < NN) ? degi[n] : 0;
    int x = v;
#pragma unroll
    for (int st = 1; st < 64; st <<= 1) {
        int y = __shfl_up(x, st, 64);
        if (lane >= st) x += y;
    }
    int total = __shfl(x, 63, 64);
    int base = 0;
    if (lane == 63) base = atomicAdd(counter, total);
    base = __shfl(base, 63, 64);
    if (n < NN) {
        int excl = base + x - v;
        row_start[n] = excl;
        cursor[n] = excl;
        invdeg[n] = 1.0f / (float)(v < 1 ? 1 : v);
    }
}

__global__ void scatter_kernel(const int* __restrict__ src, const int* __restrict__ dst,
                               const float* __restrict__ ea,
                               int* __restrict__ cursor, float4* __restrict__ csr_ea4,
                               int* __restrict__ csr_dst) {
    int e = blockIdx.x * blockDim.x + threadIdx.x;
    if (e < NE) {
        int d = dst[e];
        int pos = atomicAdd(&cursor[d], 1);
        float4 r;
        r.x = ea[e * ED + 0];
        r.y = ea[e * ED + 1];
        r.z = ea[e * ED + 2];
        r.w = __int_as_float(src[e]);
        csr_ea4[pos] = r;
        csr_dst[pos] = d;
    }
}

// ---------------- weight prep: transpose to [n][k] bf16 hi/lo ----------------
__global__ void wprep_kernel(const float* __restrict__ Wf, const float* __restrict__ Ws,
                             ushort_t* __restrict__ Wt_hi, ushort_t* __restrict__ Wt_lo) {
    int idx = blockIdx.x * 256 + threadIdx.x;   // l*65536 + n*128 + k
    if (idx >= NL * 512 * H) return;
    int k = idx & 127;
    int n = (idx >> 7) & 511;
    int l = idx >> 16;
    int t = n >> 7, j = n & 127;
    const float* W = (t == 0 || t == 2) ? Wf : Ws;
    int krow = (t < 2) ? k : (H + k);
    float v = W[(size_t)l * ZDH + krow * H + j];
    ushort_t hi = f2bf(v);
    Wt_hi[idx] = hi;
    Wt_lo[idx] = f2bf(v - bf2f(hi));
}

// ---------------- network ----------------

__global__ __launch_bounds__(H) void hin_kernel(const float* __restrict__ x,
                                                const float* __restrict__ Win,
                                                const float* __restrict__ bin,
                                                float* __restrict__ h,
                                                ushort_t* __restrict__ h_hi,
                                                ushort_t* __restrict__ h_lo) {
    int n = blockIdx.x;
    int j = threadIdx.x;
    __shared__ float xr[IND];
    if (j < IND) xr[j] = x[n * IND + j];
    __syncthreads();
    float acc = bin[j];
#pragma unroll
    for (int k = 0; k < IND; ++k) acc = fmaf(xr[k], Win[k * H + j], acc);
    size_t o = (size_t)n * H + j;
    h[o] = acc;
    ushort_t hi = f2bf(acc);
    h_hi[o] = hi;
    h_lo[o] = f2bf(acc - bf2f(hi));
}

// MFMA node GEMM v2, bf16x3 split. grid = (ceil(NN/128), 4 tables).
// All 4 waves of a block compute the SAME table (B rows shared via L1) over
// 128 rows; wave w owns rows [bx*128 + w*32, +32). A preloaded for all ks;
// B software-pipelined one nt ahead of the 24-MFMA burst.
__global__ __launch_bounds__(256) void node_gemm_mfma(const ushort_t* __restrict__ h_hi,
                                                      const ushort_t* __restrict__ h_lo,
                                                      const ushort_t* __restrict__ Wt_hi,
                                                      const ushort_t* __restrict__ Wt_lo,
                                                      float* __restrict__ PD2,
                                                      float* __restrict__ QS2) {
    int table = blockIdx.y;
    int wave = threadIdx.x >> 6;
    int lane = threadIdx.x & 63;
    int sub = lane & 15;
    int quad = lane >> 4;
    int m0 = blockIdx.x * 128 + wave * 32;

    const ushort_t* wh = Wt_hi + (size_t)table * 128 * H;
    const ushort_t* wl = Wt_lo + (size_t)table * 128 * H;

    // preload A fragments for all 4 k-steps (rows clamped for the tail block)
    bf8_t aHi[2][4], aLo[2][4];
#pragma unroll
    for (int mt = 0; mt < 2; ++mt) {
        int r = m0 + mt * 16 + sub;
        r = r < NN ? r : NN - 1;
#pragma unroll
        for (int ks = 0; ks < 4; ++ks) {
            size_t ao = (size_t)r * H + ks * 32 + quad * 8;
            aHi[mt][ks] = *(const bf8_t*)(h_hi + ao);
            aLo[mt][ks] = *(const bf8_t*)(h_lo + ao);
        }
    }

    f4_t acc[2][8];
#pragma unroll
    for (int a = 0; a < 2; ++a)
#pragma unroll
        for (int b = 0; b < 8; ++b) acc[a][b] = (f4_t){0.f, 0.f, 0.f, 0.f};

    bf8_t bHi[4], bLo[4];
#pragma unroll
    for (int ks = 0; ks < 4; ++ks) {
        size_t bo = (size_t)sub * H + ks * 32 + quad * 8;
        bHi[ks] = *(const bf8_t*)(wh + bo);
        bLo[ks] = *(const bf8_t*)(wl + bo);
    }

#pragma unroll
    for (int nt = 0; nt < 8; ++nt) {
        bf8_t nHi[4], nLo[4];
        if (nt < 7) {
#pragma unroll
            for (int ks = 0; ks < 4; ++ks) {
                size_t bo = (size_t)((nt + 1) * 16 + sub) * H + ks * 32 + quad * 8;
                nHi[ks] = *(const bf8_t*)(wh + bo);
                nLo[ks] = *(const bf8_t*)(wl + bo);
            }
        }
#pragma unroll
        for (int ks = 0; ks < 4; ++ks)
#pragma unroll
            for (int mt = 0; mt < 2; ++mt) {
                acc[mt][nt] = __builtin_amdgcn_mfma_f32_16x16x32_bf16(aHi[mt][ks], bHi[ks], acc[mt][nt], 0, 0, 0);
                acc[mt][nt] = __builtin_amdgcn_mfma_f32_16x16x32_bf16(aLo[mt][ks], bHi[ks], acc[mt][nt], 0, 0, 0);
                acc[mt][nt] = __builtin_amdgcn_mfma_f32_16x16x32_bf16(aHi[mt][ks], bLo[ks], acc[mt][nt], 0, 0, 0);
            }
#pragma unroll
        for (int ks = 0; ks < 4; ++ks) { bHi[ks] = nHi[ks]; bLo[ks] = nLo[ks]; }
    }

    float* outp = (table < 2) ? PD2 : QS2;
    int par = table & 1;
    if (m0 < NN) {
#pragma unroll
        for (int mt = 0; mt < 2; ++mt)
#pragma unroll
            for (int nt = 0; nt < 8; ++nt) {
                int col2 = 2 * (nt * 16 + sub) + par;
#pragma unroll
                for (int r = 0; r < 4; ++r) {
                    int row = m0 + mt * 16 + quad * 4 + r;
                    if (row < NN) outp[(size_t)row * 256 + col2] = acc[mt][nt][r];
                }
            }
    }
}

// Edge-parallel segmented CSR aggregation (unchanged from R8 except: zeroes
// sum/sumsq in block 0, replacing a per-layer memset dispatch).
__global__ __launch_bounds__(256) void agg_edge_kernel(const int4* __restrict__ csr_fe,
                                                       const int* __restrict__ csr_dst,
                                                       const float* __restrict__ Wf,
                                                       const float* __restrict__ bf,
                                                       const float* __restrict__ Ws,
                                                       const float* __restrict__ bs,
                                                       const float4* __restrict__ PD2_4,
                                                       const float4* __restrict__ QS2_4,
                                                       const float* __restrict__ invdeg,
                                                       float* __restrict__ h,
                                                       float* __restrict__ sum,
                                                       float* __restrict__ sumsq) {
    int tid = threadIdx.x;
    if (blockIdx.x == 0 && tid < H) { sum[tid] = 0.0f; sumsq[tid] = 0.0f; }
    int lane = tid & 63;
    int wv = tid >> 6;
    int base = (blockIdx.x * 4 + wv) * 32;
    int c0 = 2 * lane;

    float2 wf0 = *(const float2*)&Wf[256 * H + c0];
    float2 wf1 = *(const float2*)&Wf[257 * H + c0];
    float2 wf2 = *(const float2*)&Wf[258 * H + c0];
    float2 ws0 = *(const float2*)&Ws[256 * H + c0];
    float2 ws1 = *(const float2*)&Ws[257 * H + c0];
    float2 ws2 = *(const float2*)&Ws[258 * H + c0];
    float2 bf2_ = *(const float2*)&bf[c0];
    float2 bs2_ = *(const float2*)&bs[c0];

    int4 fe = csr_fe[base + (lane & 31)];
    int   dd = csr_dst[base + (lane & 31)];

    float4 q[8], p[8];
#pragma unroll
    for (int i = 0; i < 8; ++i) {
        int s = __builtin_amdgcn_readlane(fe.w, i);
        int d = __builtin_amdgcn_readlane(dd, i);
        q[i] = QS2_4[(size_t)s * 64 + lane];
        p[i] = PD2_4[(size_t)d * 64 + lane];
    }

    int dcur = __builtin_amdgcn_readlane(dd, 0);
    float acc0 = 0.f, acc1 = 0.f;

#pragma unroll
    for (int tb = 0; tb < 32; tb += 8) {
#pragma unroll
        for (int i = 0; i < 8; ++i) {
            int t = tb + i;
            int d = __builtin_amdgcn_readlane(dd, t);
            if (d != dcur) {   // wave-uniform branch
                float inv = invdeg[dcur];
                atomicAdd(&h[(size_t)dcur * H + c0], acc0 * inv);
                atomicAdd(&h[(size_t)dcur * H + c0 + 1], acc1 * inv);
                acc0 = 0.f; acc1 = 0.f;
                dcur = d;
            }
            float ex = __int_as_float(__builtin_amdgcn_readlane(fe.x, t));
            float ey = __int_as_float(__builtin_amdgcn_readlane(fe.y, t));
            float ez = __int_as_float(__builtin_amdgcn_readlane(fe.z, t));
            float4 qq = q[i], pp = p[i];
            if (t + 8 < 32) {
                int s2 = __builtin_amdgcn_readlane(fe.w, t + 8);
                int d2 = __builtin_amdgcn_readlane(dd, t + 8);
                q[i] = QS2_4[(size_t)s2 * 64 + lane];
                p[i] = PD2_4[(size_t)d2 * 64 + lane];
            }
            float f0 = fmaf(ex, wf0.x, fmaf(ey, wf1.x, fmaf(ez, wf2.x, pp.x + bf2_.x + qq.x)));
            float v0 = fmaf(ex, ws0.x, fmaf(ey, ws1.x, fmaf(ez, ws2.x, pp.y + bs2_.x + qq.y)));
            float f1 = fmaf(ex, wf0.y, fmaf(ey, wf1.y, fmaf(ez, wf2.y, pp.z + bf2_.y + qq.z)));
            float v1 = fmaf(ex, ws0.y, fmaf(ey, ws1.y, fmaf(ez, ws2.y, pp.w + bs2_.y + qq.w)));
            float sig0 = __builtin_amdgcn_rcpf(1.0f + __expf(-f0));
            float sp0  = fmaxf(v0, 0.0f) + __logf(1.0f + __expf(-fabsf(v0)));
            float sig1 = __builtin_amdgcn_rcpf(1.0f + __expf(-f1));
            float sp1  = fmaxf(v1, 0.0f) + __logf(1.0f + __expf(-fabsf(v1)));
            acc0 = fmaf(sig0, sp0, acc0);
            acc1 = fmaf(sig1, sp1, acc1);
        }
    }
    float inv = invdeg[dcur];
    atomicAdd(&h[(size_t)dcur * H + c0], acc0 * inv);
    atomicAdd(&h[(size_t)dcur * H + c0 + 1], acc1 * inv);
}

// per-column sum / sumsq; 4 independent row loads per iteration.
__global__ __launch_bounds__(H) void stats_kernel(const float* __restrict__ h,
                                                  float* __restrict__ sum,
                                                  float* __restrict__ sumsq) {
    int j = threadIdx.x;
    float s = 0.0f, ss = 0.0f;
    int n = blockIdx.x * 4;
    for (; n + 3 < NN; n += gridDim.x * 4) {
        float v0 = h[(size_t)(n + 0) * H + j];
        float v1 = h[(size_t)(n + 1) * H + j];
        float v2 = h[(size_t)(n + 2) * H + j];
        float v3 = h[(size_t)(n + 3) * H + j];
        s += (v0 + v1) + (v2 + v3);
        ss = fmaf(v0, v0, ss); ss = fmaf(v1, v1, ss);
        ss = fmaf(v2, v2, ss); ss = fmaf(v3, v3, ss);
    }
    for (; n < NN; ++n) {
        float v = h[(size_t)n * H + j];
        s += v;
        ss = fmaf(v, v, ss);
    }
    atomicAdd(&sum[j], s);
    atomicAdd(&sumsq[j], ss);
}

// BN+ReLU in place on h, also emits bf16 hi/lo for the next layer's MFMA.
__global__ __launch_bounds__(256) void bnconv_kernel(float* __restrict__ h,
                                                     const float* __restrict__ sum,
                                                     const float* __restrict__ sumsq,
                                                     const float* __restrict__ gamma,
                                                     const float* __restrict__ beta,
                                                     ushort_t* __restrict__ h_hi,
                                                     ushort_t* __restrict__ h_lo) {
    int idx0 = blockIdx.x * 256 + threadIdx.x;
    int j = idx0 & 127;
    float mu  = sum[j] * (1.0f / NN);
    float var = sumsq[j] * (1.0f / NN) - mu * mu;
    float sc  = gamma[j] * rsqrtf(var + BN_EPSF);
    float sh  = beta[j] - mu * sc;
    for (int idx = idx0; idx < NN * H; idx += gridDim.x * 256) {
        float v = fmaf(h[idx], sc, sh);
        v = v > 0.0f ? v : 0.0f;
        h[idx] = v;
        ushort_t hi = f2bf(v);
        h_hi[idx] = hi;
        h_lo[idx] = f2bf(v - bf2f(hi));
    }
}

__global__ __launch_bounds__(H) void pool_kernel(const float* __restrict__ h,
                                                 const int* __restrict__ batch,
                                                 const float* __restrict__ sum,
                                                 const float* __restrict__ sumsq,
                                                 const float* __restrict__ gamma,
                                                 const float* __restrict__ beta,
                                                 float* __restrict__ g,
                                                 float* __restrict__ cnt) {
    int j = threadIdx.x;
    float mu  = sum[j] * (1.0f / NN);
    float var = sumsq[j] * (1.0f / NN) - mu * mu;
    float sc  = gamma[j] * rsqrtf(var + BN_EPSF);
    float sh  = beta[j] - mu * sc;
    for (int n = blockIdx.x; n < NN; n += gridDim.x) {
        int b = batch[n];
        float v = fmaf(h[(size_t)n * H + j], sc, sh);
        v = v > 0.0f ? v : 0.0f;
        atomicAdd(&g[(size_t)b * H + j], v);
        if (j == 0) atomicAdd(&cnt[b], 1.0f);
    }
}

__global__ __launch_bounds__(H) void mlp_kernel(const float* __restrict__ g,
                                                const float* __restrict__ cnt,
                                                const float* __restrict__ W1,
                                                const float* __restrict__ b1,
                                                const float* __restrict__ W2,
                                                const float* __restrict__ b2,
                                                const float* __restrict__ W3,
                                                const float* __restrict__ b3,
                                                float* __restrict__ out) {
    int gid = blockIdx.x, j = threadIdx.x;
    __shared__ float s1[H];
    __shared__ float s2[H];
    __shared__ float wsum[2];
    float c = cnt[gid];
    c = c < 1.0f ? 1.0f : c;
    s1[j] = g[gid * H + j] / c;
    __syncthreads();
    float a = b1[j];
    for (int k = 0; k < H; ++k) a = fmaf(s1[k], W1[k * H + j], a);
    a = a > 0.0f ? a : 0.0f;
    s2[j] = a;
    __syncthreads();
    float t = b2[j];
    for (int k = 0; k < H; ++k) t = fmaf(s2[k], W2[k * H + j], t);
    t = t > 0.0f ? t : 0.0f;
    float p = t * W3[j];
    for (int off = 32; off > 0; off >>= 1) p += __shfl_down(p, off, 64);
    if ((j & 63) == 0) wsum[j >> 6] = p;
    __syncthreads();
    if (j == 0) out[gid] = wsum[0] + wsum[1] + b3[0];
}

extern "C" void kernel_launch(void* const* d_in, const int* in_sizes, int n_in,
                              void* d_out, int out_size, void* d_ws, size_t ws_size,
                              hipStream_t stream) {
    const float* x     = (const float*)d_in[0];
    const int*   ei    = (const int*)d_in[1];
    const int*   srcp  = ei;        // edge_index[0] = source (x_j)
    const int*   dstp  = ei + NE;   // edge_index[1] = target (aggregation index)
    const int*   batch = (const int*)d_in[2];
    const float* ea    = (const float*)d_in[3];
    const float* Win   = (const float*)d_in[4];
    const float* bin   = (const float*)d_in[5];
    const float* Wf    = (const float*)d_in[6];
    const float* bf    = (const float*)d_in[7];
    const float* Ws    = (const float*)d_in[8];
    const float* bs    = (const float*)d_in[9];
    const float* gamma = (const float*)d_in[10];
    const float* beta  = (const float*)d_in[11];
    const float* W1    = (const float*)d_in[12];
    const float* b1    = (const float*)d_in[13];
    const float* W2    = (const float*)d_in[14];
    const float* b2    = (const float*)d_in[15];
    const float* W3    = (const float*)d_in[16];
    const float* b3    = (const float*)d_in[17];
    float* out = (float*)d_out;

    const size_t NH = (size_t)NN * H;
    float* wsp = (float*)d_ws;
    size_t off = 0;
    float* h      = wsp + off; off += NH;
    float* PD2    = wsp + off; off += 2 * NH;
    float* QS2    = wsp + off; off += 2 * NH;
    float* invdeg = wsp + off; off += NN;
    float* sum    = wsp + off; off += H;
    float* sumsq  = wsp + off; off += H;
    float* g      = wsp + off; off += (size_t)NG * H;
    float* cnt    = wsp + off; off += NG;
    off = (off + 3) & ~(size_t)3;
    float4* csr_ea4 = (float4*)(wsp + off); off += (size_t)NE * 4;
    int* degi      = (int*)(wsp + off); off += NN;
    int* counter   = (int*)(wsp + off); off += 1;
    int* row_start = (int*)(wsp + off); off += NN;
    int* cursor    = (int*)(wsp + off); off += NN;
    int* csr_dst   = (int*)(wsp + off); off += NE;
    off = (off + 3) & ~(size_t)3;
    ushort_t* h_hi  = (ushort_t*)(wsp + off); off += NH / 2;
    ushort_t* h_lo  = (ushort_t*)(wsp + off); off += NH / 2;
    ushort_t* Wt_hi = (ushort_t*)(wsp + off); off += (size_t)NL * 512 * H / 2;
    ushort_t* Wt_lo = (ushort_t*)(wsp + off); off += (size_t)NL * 512 * H / 2;

    // ---- CSR + weight prep (topology/weights fixed across layers) ----
    hipMemsetAsync(degi, 0, (NN + 1) * sizeof(int), stream);  // degi + counter
    deg_int_kernel<<<(NE + 255) / 256, 256, 0, stream>>>(dstp, degi);
    reserve_kernel<<<(NN + 255) / 256, 256, 0, stream>>>(degi, row_start, cursor, invdeg, counter);
    scatter_kernel<<<(NE + 255) / 256, 256, 0, stream>>>(srcp, dstp, ea, cursor, csr_ea4, csr_dst);
    wprep_kernel<<<(NL * 512 * H + 255) / 256, 256, 0, stream>>>(Wf, Ws, Wt_hi, Wt_lo);

    hin_kernel<<<NN, H, 0, stream>>>(x, Win, bin, h, h_hi, h_lo);

    for (int l = 0; l < NL; ++l) {
        node_gemm_mfma<<<dim3((NN + 127) / 128, 4), 256, 0, stream>>>(
            h_hi, h_lo,
            Wt_hi + (size_t)l * 512 * H,
            Wt_lo + (size_t)l * 512 * H,
            PD2, QS2);
        agg_edge_kernel<<<NE / 128, 256, 0, stream>>>((const int4*)csr_ea4, csr_dst,
                                                      Wf + (size_t)l * ZDH, bf + (size_t)l * H,
                                                      Ws + (size_t)l * ZDH, bs + (size_t)l * H,
                                                      (const float4*)PD2, (const float4*)QS2,
                                                      invdeg, h, sum, sumsq);
        stats_kernel<<<512, H, 0, stream>>>(h, sum, sumsq);
        if (l < NL - 1)
            bnconv_kernel<<<1280, 256, 0, stream>>>(h, sum, sumsq,
                                                    gamma + (size_t)l * H, beta + (size_t)l * H,
                                                    h_hi, h_lo);
    }

    hipMemsetAsync(g, 0, ((size_t)NG * H + NG) * sizeof(float), stream);
    pool_kernel<<<2048, H, 0, stream>>>(h, batch, sum, sumsq,
                                        gamma + (size_t)(NL - 1) * H,
                                        beta + (size_t)(NL - 1) * H, g, cnt);
    mlp_kernel<<<NG, H, 0, stream>>>(g, cnt, W1, b1, W2, b2, W3, b3, out);
}